// Round 1
// baseline (1417.439 us; speedup 1.0000x reference)
//
#include <hip/hip_runtime.h>
#include <hip/hip_bf16.h>

// LoRA transformer: L=8, D=1024, H=16, HD=64, R=16, B=2, S=1024.
// Strategy: bf16 MFMA (16x16x32) for all matmuls, fp32 residual stream.
// Per layer: merge_T (LoRA merge + transpose to B^T bf16), gemm1 (qkv),
// vtrans (V -> V^T), attn (flash-style MFMA), gemm2 (proj + residual).

typedef unsigned short ushort_t;
typedef __attribute__((ext_vector_type(8))) short bf16x8;
typedef __attribute__((ext_vector_type(4))) float f32x4;

__device__ __forceinline__ unsigned short f2bf(float f) {
    union { float f; unsigned int u; } x; x.f = f;
    unsigned int r = x.u + 0x7fffu + ((x.u >> 16) & 1u);  // RNE
    return (unsigned short)(r >> 16);
}

__device__ __forceinline__ f32x4 mfma16(bf16x8 a, bf16x8 b, f32x4 c) {
    return __builtin_amdgcn_mfma_f32_16x16x32_bf16(a, b, c, 0, 0, 0);
}

// ---------------- convert fp32 -> bf16 (x -> h_bf16 once) ----------------
__global__ __launch_bounds__(256) void f32_to_bf16_vec(
    const float4* __restrict__ in, ushort4* __restrict__ out, int n4) {
    int i = blockIdx.x * 256 + threadIdx.x;
    if (i < n4) {
        float4 v = in[i];
        ushort4 o;
        o.x = f2bf(v.x); o.y = f2bf(v.y); o.z = f2bf(v.z); o.w = f2bf(v.w);
        out[i] = o;
    }
}

// ------------- LoRA merge + transpose: WT[n][k] = bf16(W[k][n] + A[k][:]·B[:][n]) -------------
// W: [1024][N] f32, A: [1024][16] f32, Bm: [16][N] f32, WT: [N][1024] bf16
__global__ __launch_bounds__(256) void merge_T(
    const float* __restrict__ W, const float* __restrict__ A,
    const float* __restrict__ Bm, unsigned short* __restrict__ WT, int N) {
    __shared__ float t[32][33];
    int j0 = blockIdx.x * 32, i0 = blockIdx.y * 32;
    int tx = threadIdx.x & 31, ty = threadIdx.x >> 5;  // 32 x 8
    for (int ii = ty; ii < 32; ii += 8) {
        int i = i0 + ii;
        float acc = W[(size_t)i * N + j0 + tx];
        #pragma unroll
        for (int r = 0; r < 16; r++)
            acc += A[i * 16 + r] * Bm[(size_t)r * N + j0 + tx];
        t[ii][tx] = acc;
    }
    __syncthreads();
    for (int jj = ty; jj < 32; jj += 8)
        WT[(size_t)(j0 + jj) * 1024 + i0 + tx] = f2bf(t[tx][jj]);
}

// ------------- GEMM: C[M][N] = A[M][K] @ BT[N][K]^T, bf16 in, fp32 acc -------------
// 128x128 tile, BK=32, 4 waves (2x2), each wave 64x64 via 4x4 MFMAs.
// LDS rows padded to 40 bf16 (80B, 16B-aligned, 2-way bank alias = free).
__global__ __launch_bounds__(256) void gemm_bf16(
    const unsigned short* __restrict__ A,   // [M][K]
    const unsigned short* __restrict__ BT,  // [N][K]
    const float* __restrict__ res,          // [M][N] residual or null
    float* __restrict__ outF,               // [M][N] fp32 out or null
    unsigned short* __restrict__ outB,      // [M][N] bf16 out or null
    int M, int N, int K) {
    __shared__ __align__(16) unsigned short As[128 * 40];
    __shared__ __align__(16) unsigned short Bs[128 * 40];
    const int tid = threadIdx.x;
    const int m0 = blockIdx.y * 128, n0 = blockIdx.x * 128;
    const int w = tid >> 6, lane = tid & 63;
    const int wm = (w >> 1) * 64, wn = (w & 1) * 64;
    const int lr = lane & 15, quad = lane >> 4;
    const int r0 = tid >> 2;            // 0..63
    const int kof = (tid & 3) * 8;      // 0,8,16,24

    f32x4 acc[4][4] = {};

    for (int k0 = 0; k0 < K; k0 += 32) {
        uint4 a0 = *(const uint4*)(A  + (size_t)(m0 + r0)      * K + k0 + kof);
        uint4 a1 = *(const uint4*)(A  + (size_t)(m0 + r0 + 64) * K + k0 + kof);
        uint4 b0 = *(const uint4*)(BT + (size_t)(n0 + r0)      * K + k0 + kof);
        uint4 b1 = *(const uint4*)(BT + (size_t)(n0 + r0 + 64) * K + k0 + kof);
        __syncthreads();  // previous iter's reads done before overwrite
        *(uint4*)&As[(r0)      * 40 + kof] = a0;
        *(uint4*)&As[(r0 + 64) * 40 + kof] = a1;
        *(uint4*)&Bs[(r0)      * 40 + kof] = b0;
        *(uint4*)&Bs[(r0 + 64) * 40 + kof] = b1;
        __syncthreads();
        bf16x8 af[4], bfr[4];
        #pragma unroll
        for (int i = 0; i < 4; i++) {
            af[i]  = *(const bf16x8*)&As[(wm + i * 16 + lr) * 40 + quad * 8];
            bfr[i] = *(const bf16x8*)&Bs[(wn + i * 16 + lr) * 40 + quad * 8];
        }
        #pragma unroll
        for (int i = 0; i < 4; i++)
            #pragma unroll
            for (int j = 0; j < 4; j++)
                acc[i][j] = mfma16(af[i], bfr[j], acc[i][j]);
    }
    // epilogue: C/D layout row = quad*4+r, col = lane&15  (verified m89/m91)
    #pragma unroll
    for (int i = 0; i < 4; i++)
        #pragma unroll
        for (int j = 0; j < 4; j++)
            #pragma unroll
            for (int r = 0; r < 4; r++) {
                int row = m0 + wm + i * 16 + quad * 4 + r;
                int col = n0 + wn + j * 16 + lr;
                float v = acc[i][j][r];
                if (res)  v += res[(size_t)row * N + col];
                if (outF) outF[(size_t)row * N + col] = v;
                if (outB) outB[(size_t)row * N + col] = f2bf(v);
            }
}

// ------------- V transpose: VT[bh][d][s] = qkv[b*1024+s][2048 + h*64 + d] -------------
__global__ __launch_bounds__(256) void vtrans(
    const unsigned short* __restrict__ qkv, unsigned short* __restrict__ VT) {
    __shared__ unsigned short t[32][33];
    int bh = blockIdx.z, b = bh >> 4, h = bh & 15;
    int s0 = blockIdx.x * 32, d0 = blockIdx.y * 32;
    int tx = threadIdx.x & 31, ty = threadIdx.x >> 5;
    for (int i = ty; i < 32; i += 8)
        t[i][tx] = qkv[(size_t)(b * 1024 + s0 + i) * 3072 + 2048 + h * 64 + d0 + tx];
    __syncthreads();
    for (int i = ty; i < 32; i += 8)
        VT[((size_t)bh * 64 + d0 + i) * 1024 + s0 + tx] = t[tx][i];
}

// ------------- Flash attention, MFMA 16x16x32, causal -------------
// Block = 4 waves; wave = 16 q-rows. K-tiles of 32. Q,K read from qkv bf16;
// V from VT (pre-transposed). P round-trips C-layout -> A-layout via LDS.
__global__ __launch_bounds__(256) void attn_kernel(
    const unsigned short* __restrict__ qkv,  // [2048][3072]
    const unsigned short* __restrict__ VT,   // [32][64][1024]
    unsigned short* __restrict__ O) {        // [2048][1024]
    __shared__ __align__(16) unsigned short pl[4][16 * 40];
    const int tid = threadIdx.x;
    const int w = tid >> 6, lane = tid & 63;
    const int lr = lane & 15, quad = lane >> 4;
    const int bh = blockIdx.y, b = bh >> 4, h = bh & 15;
    const int qb = blockIdx.x * 64 + w * 16;
    const float LOG2E = 1.44269504f;

    const size_t rowQ = (size_t)(b * 1024 + qb + lr) * 3072 + h * 64;
    bf16x8 aq0 = *(const bf16x8*)&qkv[rowQ + quad * 8];
    bf16x8 aq1 = *(const bf16x8*)&qkv[rowQ + 32 + quad * 8];

    float m_i[4], l_i[4];
    f32x4 oacc[4] = {};
    #pragma unroll
    for (int r = 0; r < 4; r++) { m_i[r] = -1e30f; l_i[r] = 0.f; }

    const int kt_end = qb + 16;  // causal: need k <= qb+15
    for (int kt = 0; kt < kt_end; kt += 32) {
        f32x4 s[2] = {};
        #pragma unroll
        for (int nh = 0; nh < 2; nh++) {
            const size_t rowK = (size_t)(b * 1024 + kt + nh * 16 + lr) * 3072 + 1024 + h * 64;
            bf16x8 kb0 = *(const bf16x8*)&qkv[rowK + quad * 8];
            bf16x8 kb1 = *(const bf16x8*)&qkv[rowK + 32 + quad * 8];
            s[nh] = mfma16(aq0, kb0, s[nh]);
            s[nh] = mfma16(aq1, kb1, s[nh]);
        }
        float mx[4];
        #pragma unroll
        for (int r = 0; r < 4; r++) {
            int qrow = qb + quad * 4 + r;
            #pragma unroll
            for (int nh = 0; nh < 2; nh++) {
                int kcol = kt + nh * 16 + lr;
                float v = s[nh][r] * 0.125f;  // 1/sqrt(64)
                s[nh][r] = (kcol <= qrow) ? v : -1e30f;
            }
            mx[r] = fmaxf(s[0][r], s[1][r]);
        }
        #pragma unroll
        for (int d = 1; d < 16; d <<= 1) {
            #pragma unroll
            for (int r = 0; r < 4; r++) mx[r] = fmaxf(mx[r], __shfl_xor(mx[r], d));
        }
        float al[4], rs[4];
        #pragma unroll
        for (int r = 0; r < 4; r++) {
            float mnew = fmaxf(m_i[r], mx[r]);
            al[r] = exp2f((m_i[r] - mnew) * LOG2E);
            m_i[r] = mnew;
            float p0 = exp2f((s[0][r] - mnew) * LOG2E);
            float p1 = exp2f((s[1][r] - mnew) * LOG2E);
            s[0][r] = p0; s[1][r] = p1;
            rs[r] = p0 + p1;
        }
        #pragma unroll
        for (int d = 1; d < 16; d <<= 1) {
            #pragma unroll
            for (int r = 0; r < 4; r++) rs[r] += __shfl_xor(rs[r], d);
        }
        #pragma unroll
        for (int r = 0; r < 4; r++) l_i[r] = l_i[r] * al[r] + rs[r];
        #pragma unroll
        for (int dt = 0; dt < 4; dt++)
            #pragma unroll
            for (int r = 0; r < 4; r++) oacc[dt][r] *= al[r];
        // P: C-layout -> LDS -> A-layout (wave-internal, no barrier needed)
        #pragma unroll
        for (int nh = 0; nh < 2; nh++)
            #pragma unroll
            for (int r = 0; r < 4; r++)
                pl[w][(quad * 4 + r) * 40 + nh * 16 + lr] = f2bf(s[nh][r]);
        bf16x8 ap = *(const bf16x8*)&pl[w][lr * 40 + quad * 8];
        #pragma unroll
        for (int dt = 0; dt < 4; dt++) {
            const size_t rowV = ((size_t)bh * 64 + dt * 16 + lr) * 1024 + kt + quad * 8;
            bf16x8 vb = *(const bf16x8*)&VT[rowV];
            oacc[dt] = mfma16(ap, vb, oacc[dt]);
        }
    }
    #pragma unroll
    for (int dt = 0; dt < 4; dt++)
        #pragma unroll
        for (int r = 0; r < 4; r++) {
            int row = b * 1024 + qb + quad * 4 + r;
            int col = h * 64 + dt * 16 + lr;
            O[(size_t)row * 1024 + col] = f2bf(oacc[dt][r] / l_i[r]);
        }
}

extern "C" void kernel_launch(void* const* d_in, const int* in_sizes, int n_in,
                              void* d_out, int out_size, void* d_ws, size_t ws_size,
                              hipStream_t stream) {
    const float* x     = (const float*)d_in[0];
    const float* Wqkv  = (const float*)d_in[1];
    const float* Aqkv  = (const float*)d_in[2];
    const float* Bqkv  = (const float*)d_in[3];
    const float* Wproj = (const float*)d_in[4];
    const float* Aproj = (const float*)d_in[5];
    const float* Bproj = (const float*)d_in[6];
    float* out = (float*)d_out;

    char* ws = (char*)d_ws;
    float* h_f32 = (float*)ws;                 ws += (size_t)2048 * 1024 * 4;  // 8 MB
    unsigned short* h_bf  = (unsigned short*)ws; ws += (size_t)2048 * 1024 * 2;  // 4 MB
    unsigned short* qkv_bf = (unsigned short*)ws; ws += (size_t)2048 * 3072 * 2; // 12 MB
    unsigned short* VT   = (unsigned short*)ws; ws += (size_t)32 * 64 * 1024 * 2; // 4 MB
    unsigned short* O_bf = (unsigned short*)ws; ws += (size_t)2048 * 1024 * 2;  // 4 MB
    unsigned short* WqT  = (unsigned short*)ws; ws += (size_t)3072 * 1024 * 2;  // 6 MB
    unsigned short* WpT  = (unsigned short*)ws; ws += (size_t)1024 * 1024 * 2;  // 2 MB

    hipMemcpyAsync(h_f32, x, (size_t)2048 * 1024 * 4, hipMemcpyDeviceToDevice, stream);
    f32_to_bf16_vec<<<2048, 256, 0, stream>>>((const float4*)x, (ushort4*)h_bf,
                                              2048 * 1024 / 4);

    for (int l = 0; l < 8; l++) {
        const float* Wq = Wqkv  + (size_t)l * 1024 * 3072;
        const float* Aq = Aqkv  + (size_t)l * 1024 * 16;
        const float* Bq = Bqkv  + (size_t)l * 16 * 3072;
        const float* Wp = Wproj + (size_t)l * 1024 * 1024;
        const float* Ap = Aproj + (size_t)l * 1024 * 16;
        const float* Bp = Bproj + (size_t)l * 16 * 1024;

        merge_T<<<dim3(96, 32), 256, 0, stream>>>(Wq, Aq, Bq, WqT, 3072);
        merge_T<<<dim3(32, 32), 256, 0, stream>>>(Wp, Ap, Bp, WpT, 1024);
        gemm_bf16<<<dim3(24, 16), 256, 0, stream>>>(h_bf, WqT, nullptr, nullptr,
                                                    qkv_bf, 2048, 3072, 1024);
        vtrans<<<dim3(32, 2, 32), 256, 0, stream>>>(qkv_bf, VT);
        attn_kernel<<<dim3(16, 32), 256, 0, stream>>>(qkv_bf, VT, O_bf);
        float* outF = (l == 7) ? out : h_f32;
        gemm_bf16<<<dim3(8, 16), 256, 0, stream>>>(O_bf, WpT, h_f32, outF, h_bf,
                                                   2048, 1024, 1024);
    }
}

// Round 3
// 1056.019 us; speedup vs baseline: 1.3422x; 1.3422x over previous
//
#include <hip/hip_runtime.h>
#include <hip/hip_bf16.h>

// LoRA transformer: L=8, D=1024, H=16, HD=64, R=16, B=2, S=1024.
// bf16 MFMA everywhere, fp32 residual stream.
// R2: fix attn pairing OOB (t pairs 63-t, grid 8x32), add K/V register
// software pipeline in attn. GEMM keeps global_load_lds (m97) staging.

typedef unsigned short ushort_t;
typedef __attribute__((ext_vector_type(8))) short bf16x8;
typedef __attribute__((ext_vector_type(4))) float f32x4;

__device__ __forceinline__ unsigned short f2bf(float f) {
    union { float f; unsigned int u; } x; x.f = f;
    unsigned int r = x.u + 0x7fffu + ((x.u >> 16) & 1u);  // RNE
    return (unsigned short)(r >> 16);
}

__device__ __forceinline__ f32x4 mfma16(bf16x8 a, bf16x8 b, f32x4 c) {
    return __builtin_amdgcn_mfma_f32_16x16x32_bf16(a, b, c, 0, 0, 0);
}

typedef const __attribute__((address_space(1))) unsigned int* gas_ptr;
typedef __attribute__((address_space(3))) unsigned int* las_ptr;
// async global->LDS, 16B/lane; LDS dest = wave-uniform base + lane*16 (m104/m108)
__device__ __forceinline__ void lds_stage16(const void* g, void* l) {
    __builtin_amdgcn_global_load_lds((gas_ptr)(unsigned long long)g,
                                     (las_ptr)(unsigned int)(unsigned long long)l,
                                     16, 0, 0);
}

// ---------------- fp32 -> bf16 ----------------
__global__ __launch_bounds__(256) void f32_to_bf16_vec(
    const float4* __restrict__ in, ushort4* __restrict__ out, int n4) {
    int i = blockIdx.x * 256 + threadIdx.x;
    if (i < n4) {
        float4 v = in[i];
        ushort4 o;
        o.x = f2bf(v.x); o.y = f2bf(v.y); o.z = f2bf(v.z); o.w = f2bf(v.w);
        out[i] = o;
    }
}

// ------------- LoRA merge + transpose: WT[n][k] = bf16(W[k][n] + A[k][:]·B[:][n]) -------------
__global__ __launch_bounds__(256) void merge_T(
    const float* __restrict__ W, const float* __restrict__ A,
    const float* __restrict__ Bm, unsigned short* __restrict__ WT, int N) {
    __shared__ float t[32][33];
    int j0 = blockIdx.x * 32, i0 = blockIdx.y * 32;
    int tx = threadIdx.x & 31, ty = threadIdx.x >> 5;  // 32 x 8
    for (int ii = ty; ii < 32; ii += 8) {
        int i = i0 + ii;
        float acc = W[(size_t)i * N + j0 + tx];
        #pragma unroll
        for (int r = 0; r < 16; r++)
            acc += A[i * 16 + r] * Bm[(size_t)r * N + j0 + tx];
        t[ii][tx] = acc;
    }
    __syncthreads();
    for (int jj = ty; jj < 32; jj += 8)
        WT[(size_t)(j0 + jj) * 1024 + i0 + tx] = f2bf(t[tx][jj]);
}

// ------------- GEMM: C[M][N] = A[M][K] @ BT[N][K]^T -------------
// 64x128 tile, BK=32, 4 waves 2x2, wave tile 32x64 (2x4 MFMAs).
// LDS unpadded 64B rows (global_load_lds requirement); staged 16B/lane.
__global__ __launch_bounds__(256) void gemm_bf16(
    const unsigned short* __restrict__ A,   // [M][K]
    const unsigned short* __restrict__ BT,  // [N][K]
    const float* __restrict__ res,          // [M][N] residual or null
    float* __restrict__ outF,               // fp32 out or null
    unsigned short* __restrict__ outB,      // bf16 out or null
    int M, int N, int K, int scaleq) {
    constexpr int BM = 64, BN = 128;
    __shared__ __align__(16) unsigned short As[BM * 32];
    __shared__ __align__(16) unsigned short Bs[BN * 32];
    const int tid = threadIdx.x;
    const int m0 = blockIdx.y * BM, n0 = blockIdx.x * BN;
    const int w = tid >> 6, lane = tid & 63;
    const int wm = (w >> 1) * 32, wn = (w & 1) * 64;
    const int lr = lane & 15, quad = lane >> 4;

    // staging geometry: tile A = 4096 B, tile B = 8192 B
    const int loff = w * 1024 + lane * 16;                // lane byte offset in pass
    const int srow = loff >> 6, skof = (loff & 63) >> 1;  // row, ushort k-offset

    f32x4 acc[2][4] = {};

    for (int k0 = 0; k0 < K; k0 += 32) {
        __syncthreads();  // previous iter's frag reads done
        lds_stage16(A + (size_t)(m0 + srow) * K + k0 + skof,
                    (char*)As + w * 1024);
        lds_stage16(BT + (size_t)(n0 + srow) * K + k0 + skof,
                    (char*)Bs + w * 1024);
        lds_stage16(BT + (size_t)(n0 + 64 + srow) * K + k0 + skof,
                    (char*)Bs + 4096 + w * 1024);
        __syncthreads();  // compiler drains vmcnt(0) before s_barrier

        bf16x8 af[2], bfr[4];
        #pragma unroll
        for (int i = 0; i < 2; i++)
            af[i] = *(const bf16x8*)&As[(wm + i * 16 + lr) * 32 + quad * 8];
        #pragma unroll
        for (int j = 0; j < 4; j++)
            bfr[j] = *(const bf16x8*)&Bs[(wn + j * 16 + lr) * 32 + quad * 8];
        #pragma unroll
        for (int i = 0; i < 2; i++)
            #pragma unroll
            for (int j = 0; j < 4; j++)
                acc[i][j] = mfma16(af[i], bfr[j], acc[i][j]);
    }
    // C/D layout: row = quad*4+r, col = lane&15 (m89/m91)
    #pragma unroll
    for (int i = 0; i < 2; i++)
        #pragma unroll
        for (int j = 0; j < 4; j++)
            #pragma unroll
            for (int r = 0; r < 4; r++) {
                int row = m0 + wm + i * 16 + quad * 4 + r;
                int col = n0 + wn + j * 16 + lr;
                float v = acc[i][j][r];
                if (scaleq && col < 1024) v *= 0.125f;  // fold 1/sqrt(64) into Q
                if (res)  v += res[(size_t)row * N + col];
                if (outF) outF[(size_t)row * N + col] = v;
                if (outB) outB[(size_t)row * N + col] = f2bf(v);
            }
}

// ------------- V transpose: VT[bh][d][s] -------------
__global__ __launch_bounds__(256) void vtrans(
    const unsigned short* __restrict__ qkv, unsigned short* __restrict__ VT) {
    __shared__ unsigned short t[32][33];
    int bh = blockIdx.z, b = bh >> 4, h = bh & 15;
    int s0 = blockIdx.x * 32, d0 = blockIdx.y * 32;
    int tx = threadIdx.x & 31, ty = threadIdx.x >> 5;
    for (int i = ty; i < 32; i += 8)
        t[i][tx] = qkv[(size_t)(b * 1024 + s0 + i) * 3072 + 2048 + h * 64 + d0 + tx];
    __syncthreads();
    for (int i = ty; i < 32; i += 8)
        VT[((size_t)bh * 64 + d0 + i) * 1024 + s0 + tx] = t[tx][i];
}

// ------------- Flash attention, causal-balanced, KT=64, K-prefetch pipeline -------------
// Wave handles q-tiles t and 63-t (each wave exactly 65 k-tiles-of-16 total).
// Q pre-scaled by 1/8 in gemm1 epilogue.

#define LOADK(KT, K0, K1)                                                      \
    {                                                                          \
        _Pragma("unroll")                                                      \
        for (int nh = 0; nh < 4; nh++) {                                       \
            const size_t rowK =                                                \
                (size_t)(b * 1024 + (KT) + nh * 16 + lr) * 3072 + 1024 + h * 64; \
            K0[nh] = *(const bf16x8*)&qkv[rowK + quad * 8];                    \
            K1[nh] = *(const bf16x8*)&qkv[rowK + 32 + quad * 8];               \
        }                                                                      \
    }

#define TILE_STEP(KT, KC0, KC1, KN0, KN1, PRE)                                 \
    {                                                                          \
        const int kt_ = (KT);                                                  \
        bf16x8 vb0[4], vb1[4];                                                 \
        _Pragma("unroll")                                                      \
        for (int dt = 0; dt < 4; dt++) {                                       \
            const size_t rowV = ((size_t)bh * 64 + dt * 16 + lr) * 1024 + kt_; \
            vb0[dt] = *(const bf16x8*)&VT[rowV + quad * 8];                    \
            vb1[dt] = *(const bf16x8*)&VT[rowV + 32 + quad * 8];               \
        }                                                                      \
        if (PRE) LOADK(kt_ + 64, KN0, KN1)                                     \
        f32x4 s[4] = {};                                                       \
        _Pragma("unroll")                                                      \
        for (int nh = 0; nh < 4; nh++) {                                       \
            s[nh] = mfma16(aq0, KC0[nh], s[nh]);                               \
            s[nh] = mfma16(aq1, KC1[nh], s[nh]);                               \
        }                                                                      \
        float mx[4];                                                           \
        _Pragma("unroll")                                                      \
        for (int r = 0; r < 4; r++) {                                          \
            int qrow = qb + quad * 4 + r;                                      \
            _Pragma("unroll")                                                  \
            for (int nh = 0; nh < 4; nh++) {                                   \
                int kcol = kt_ + nh * 16 + lr;                                 \
                s[nh][r] = (kcol <= qrow) ? s[nh][r] : -1e30f;                 \
            }                                                                  \
            mx[r] = fmaxf(fmaxf(s[0][r], s[1][r]), fmaxf(s[2][r], s[3][r]));   \
        }                                                                      \
        _Pragma("unroll")                                                      \
        for (int d = 1; d < 16; d <<= 1) {                                     \
            _Pragma("unroll")                                                  \
            for (int r = 0; r < 4; r++)                                        \
                mx[r] = fmaxf(mx[r], __shfl_xor(mx[r], d));                    \
        }                                                                      \
        float al[4], rs[4];                                                    \
        _Pragma("unroll")                                                      \
        for (int r = 0; r < 4; r++) {                                          \
            float mnew = fmaxf(m_i[r], mx[r]);                                 \
            al[r] = exp2f((m_i[r] - mnew) * LOG2E);                            \
            m_i[r] = mnew;                                                     \
            float lsum = 0.f;                                                  \
            _Pragma("unroll")                                                  \
            for (int nh = 0; nh < 4; nh++) {                                   \
                float p = exp2f((s[nh][r] - mnew) * LOG2E);                    \
                s[nh][r] = p;                                                  \
                lsum += p;                                                     \
            }                                                                  \
            rs[r] = lsum;                                                      \
        }                                                                      \
        _Pragma("unroll")                                                      \
        for (int d = 1; d < 16; d <<= 1) {                                     \
            _Pragma("unroll")                                                  \
            for (int r = 0; r < 4; r++) rs[r] += __shfl_xor(rs[r], d);         \
        }                                                                      \
        _Pragma("unroll")                                                      \
        for (int r = 0; r < 4; r++) l_i[r] = l_i[r] * al[r] + rs[r];           \
        _Pragma("unroll")                                                      \
        for (int dt = 0; dt < 4; dt++) {                                       \
            _Pragma("unroll")                                                  \
            for (int r = 0; r < 4; r++) oacc[dt][r] *= al[r];                  \
        }                                                                      \
        _Pragma("unroll")                                                      \
        for (int nh = 0; nh < 4; nh++) {                                       \
            _Pragma("unroll")                                                  \
            for (int r = 0; r < 4; r++)                                        \
                pl[w][(quad * 4 + r) * 72 + nh * 16 + lr] = f2bf(s[nh][r]);    \
        }                                                                      \
        bf16x8 ap0 = *(const bf16x8*)&pl[w][lr * 72 + quad * 8];               \
        bf16x8 ap1 = *(const bf16x8*)&pl[w][lr * 72 + 32 + quad * 8];          \
        _Pragma("unroll")                                                      \
        for (int dt = 0; dt < 4; dt++) {                                       \
            oacc[dt] = mfma16(ap0, vb0[dt], oacc[dt]);                         \
            oacc[dt] = mfma16(ap1, vb1[dt], oacc[dt]);                         \
        }                                                                      \
    }

__global__ __launch_bounds__(256) void attn_kernel(
    const unsigned short* __restrict__ qkv,  // [2048][3072]
    const unsigned short* __restrict__ VT,   // [32][64][1024]
    unsigned short* __restrict__ O) {        // [2048][1024]
    __shared__ __align__(16) unsigned short pl[4][16 * 72];
    const int tid = threadIdx.x;
    const int w = tid >> 6, lane = tid & 63;
    const int lr = lane & 15, quad = lane >> 4;
    const int bh = blockIdx.y, b = bh >> 4, h = bh & 15;
    const int t = blockIdx.x * 4 + w;  // 0..31
    const float LOG2E = 1.44269504f;

    #pragma unroll
    for (int pass = 0; pass < 2; pass++) {
        const int qb = (pass ? (63 - t) : t) * 16;  // tiles 0..31 then 32..63
        const size_t rowQ = (size_t)(b * 1024 + qb + lr) * 3072 + h * 64;
        bf16x8 aq0 = *(const bf16x8*)&qkv[rowQ + quad * 8];
        bf16x8 aq1 = *(const bf16x8*)&qkv[rowQ + 32 + quad * 8];

        float m_i[4], l_i[4];
        f32x4 oacc[4] = {};
        #pragma unroll
        for (int r = 0; r < 4; r++) { m_i[r] = -1e30f; l_i[r] = 0.f; }

        const int nkt = (qb + 16 + 63) >> 6;  // 1..16 tiles of 64

        bf16x8 kA0[4], kA1[4], kB0[4], kB1[4];
        LOADK(0, kA0, kA1)
        for (int kt64 = 0; kt64 < nkt; kt64 += 2) {
            TILE_STEP(kt64 << 6, kA0, kA1, kB0, kB1, (kt64 + 1 < nkt))
            if (kt64 + 1 < nkt)
                TILE_STEP((kt64 + 1) << 6, kB0, kB1, kA0, kA1, (kt64 + 2 < nkt))
        }
        #pragma unroll
        for (int dt = 0; dt < 4; dt++)
            #pragma unroll
            for (int r = 0; r < 4; r++) {
                int row = b * 1024 + qb + quad * 4 + r;
                int col = h * 64 + dt * 16 + lr;
                O[(size_t)row * 1024 + col] = f2bf(oacc[dt][r] / l_i[r]);
            }
    }
}

extern "C" void kernel_launch(void* const* d_in, const int* in_sizes, int n_in,
                              void* d_out, int out_size, void* d_ws, size_t ws_size,
                              hipStream_t stream) {
    const float* x     = (const float*)d_in[0];
    const float* Wqkv  = (const float*)d_in[1];
    const float* Aqkv  = (const float*)d_in[2];
    const float* Bqkv  = (const float*)d_in[3];
    const float* Wproj = (const float*)d_in[4];
    const float* Aproj = (const float*)d_in[5];
    const float* Bproj = (const float*)d_in[6];
    float* out = (float*)d_out;

    char* ws = (char*)d_ws;
    float* h_f32 = (float*)ws;                    ws += (size_t)2048 * 1024 * 4;
    unsigned short* h_bf   = (unsigned short*)ws; ws += (size_t)2048 * 1024 * 2;
    unsigned short* qkv_bf = (unsigned short*)ws; ws += (size_t)2048 * 3072 * 2;
    unsigned short* VT     = (unsigned short*)ws; ws += (size_t)32 * 64 * 1024 * 2;
    unsigned short* O_bf   = (unsigned short*)ws; ws += (size_t)2048 * 1024 * 2;
    unsigned short* WqT    = (unsigned short*)ws; ws += (size_t)3072 * 1024 * 2;
    unsigned short* WpT    = (unsigned short*)ws; ws += (size_t)1024 * 1024 * 2;

    hipMemcpyAsync(h_f32, x, (size_t)2048 * 1024 * 4, hipMemcpyDeviceToDevice, stream);
    f32_to_bf16_vec<<<2048, 256, 0, stream>>>((const float4*)x, (ushort4*)h_bf,
                                              2048 * 1024 / 4);

    for (int l = 0; l < 8; l++) {
        const float* Wq = Wqkv  + (size_t)l * 1024 * 3072;
        const float* Aq = Aqkv  + (size_t)l * 1024 * 16;
        const float* Bq = Bqkv  + (size_t)l * 16 * 3072;
        const float* Wp = Wproj + (size_t)l * 1024 * 1024;
        const float* Ap = Aproj + (size_t)l * 1024 * 16;
        const float* Bp = Bproj + (size_t)l * 16 * 1024;

        merge_T<<<dim3(96, 32), 256, 0, stream>>>(Wq, Aq, Bq, WqT, 3072);
        merge_T<<<dim3(32, 32), 256, 0, stream>>>(Wp, Ap, Bp, WpT, 1024);
        // qkv GEMM: Q columns pre-scaled by 1/8
        gemm_bf16<<<dim3(24, 32), 256, 0, stream>>>(h_bf, WqT, nullptr, nullptr,
                                                    qkv_bf, 2048, 3072, 1024, 1);
        vtrans<<<dim3(32, 2, 32), 256, 0, stream>>>(qkv_bf, VT);
        attn_kernel<<<dim3(8, 32), 256, 0, stream>>>(qkv_bf, VT, O_bf);
        float* outF = (l == 7) ? out : h_f32;
        gemm_bf16<<<dim3(8, 32), 256, 0, stream>>>(O_bf, WpT, h_f32, outF, h_bf,
                                                   2048, 1024, 1024, 0);
    }
}

// Round 4
// 1019.347 us; speedup vs baseline: 1.3905x; 1.0360x over previous
//
#include <hip/hip_runtime.h>
#include <hip/hip_bf16.h>

// LoRA transformer: L=8, D=1024, H=16, HD=64, R=16, B=2, S=1024.
// bf16 MFMA everywhere, fp32 residual stream.
// R4: gemm1 -> m97-exact 128x128 tile (global_load_lds, 16 MFMA/wave/K-step);
// merge_T vectorized (float4). gemm2 stays 64x128 (grid 256). attn unchanged.

typedef unsigned short ushort_t;
typedef __attribute__((ext_vector_type(8))) short bf16x8;
typedef __attribute__((ext_vector_type(4))) float f32x4;

__device__ __forceinline__ unsigned short f2bf(float f) {
    union { float f; unsigned int u; } x; x.f = f;
    unsigned int r = x.u + 0x7fffu + ((x.u >> 16) & 1u);  // RNE
    return (unsigned short)(r >> 16);
}

__device__ __forceinline__ f32x4 mfma16(bf16x8 a, bf16x8 b, f32x4 c) {
    return __builtin_amdgcn_mfma_f32_16x16x32_bf16(a, b, c, 0, 0, 0);
}

typedef const __attribute__((address_space(1))) unsigned int* gas_ptr;
typedef __attribute__((address_space(3))) unsigned int* las_ptr;
// async global->LDS, 16B/lane; LDS dest = wave-uniform base + lane*16 (m104/m108)
__device__ __forceinline__ void lds_stage16(const void* g, void* l) {
    __builtin_amdgcn_global_load_lds((gas_ptr)(unsigned long long)g,
                                     (las_ptr)(unsigned int)(unsigned long long)l,
                                     16, 0, 0);
}

// ---------------- fp32 -> bf16 ----------------
__global__ __launch_bounds__(256) void f32_to_bf16_vec(
    const float4* __restrict__ in, ushort4* __restrict__ out, int n4) {
    int i = blockIdx.x * 256 + threadIdx.x;
    if (i < n4) {
        float4 v = in[i];
        ushort4 o;
        o.x = f2bf(v.x); o.y = f2bf(v.y); o.z = f2bf(v.z); o.w = f2bf(v.w);
        out[i] = o;
    }
}

// ------------- LoRA merge + transpose (vectorized) -------------
// WT[n][k] = bf16(W[k][n] + A[k][:] . B[:][n]).  Tile: 32 i x 128 j.
// Phase 1: float4 compute into padded LDS; Phase 2: 32B vector stores of WT.
__global__ __launch_bounds__(256) void merge_T(
    const float* __restrict__ W, const float* __restrict__ A,
    const float* __restrict__ Bm, unsigned short* __restrict__ WT, int N) {
    __shared__ float t[32][132];  // stride 132: 16B-aligned, 4-bank row shift
    int j0 = blockIdx.x * 128, i0 = blockIdx.y * 32;
    int tx = threadIdx.x & 31, ty = threadIdx.x >> 5;  // 32 x 8
    for (int ii = ty; ii < 32; ii += 8) {
        int i = i0 + ii;
        float4 acc = *(const float4*)&W[(size_t)i * N + j0 + tx * 4];
        #pragma unroll
        for (int r = 0; r < 16; r++) {
            float a = A[i * 16 + r];
            float4 bv = *(const float4*)&Bm[(size_t)r * N + j0 + tx * 4];
            acc.x += a * bv.x; acc.y += a * bv.y;
            acc.z += a * bv.z; acc.w += a * bv.w;
        }
        *(float4*)&t[ii][tx * 4] = acc;
    }
    __syncthreads();
    int jj = threadIdx.x >> 1, half = threadIdx.x & 1;  // 128 rows x 2 halves
    bf16x8 o0, o1;
    #pragma unroll
    for (int c = 0; c < 8; c++) o0[c] = (short)f2bf(t[half * 16 + c][jj]);
    #pragma unroll
    for (int c = 0; c < 8; c++) o1[c] = (short)f2bf(t[half * 16 + 8 + c][jj]);
    unsigned short* dst = &WT[(size_t)(j0 + jj) * 1024 + i0 + half * 16];
    *(bf16x8*)dst = o0;
    *(bf16x8*)(dst + 8) = o1;
}

// ------------- GEMM 128x128 (m97 structure): C = A @ BT^T -------------
// BK=32, 4 waves, wave tile 64x64 (4x4 MFMA). LDS unpadded 64B rows,
// staged via 4 global_load_lds_dwordx4 rounds (4KB each).
__global__ __launch_bounds__(256) void gemm_bf16_128(
    const unsigned short* __restrict__ A,   // [M][K]
    const unsigned short* __restrict__ BT,  // [N][K]
    unsigned short* __restrict__ outB,      // bf16 out
    int M, int N, int K, int scaleq) {
    __shared__ __align__(16) unsigned short As[128 * 32];
    __shared__ __align__(16) unsigned short Bs[128 * 32];
    const int tid = threadIdx.x;
    const int m0 = blockIdx.y * 128, n0 = blockIdx.x * 128;
    const int w = tid >> 6, lane = tid & 63;
    const int wm = (w >> 1) * 64, wn = (w & 1) * 64;
    const int lr = lane & 15, quad = lane >> 4;
    // staging: per 4KB chunk, wave w covers rows w*16 + lane/4, kofs (lane&3)*8
    const int srow = w * 16 + (lane >> 2);
    const int skof = (lane & 3) * 8;

    f32x4 acc[4][4] = {};

    for (int k0 = 0; k0 < K; k0 += 32) {
        __syncthreads();  // prev iter's frag reads done
        lds_stage16(A  + (size_t)(m0 + srow)      * K + k0 + skof, (char*)As + w * 1024);
        lds_stage16(A  + (size_t)(m0 + 64 + srow) * K + k0 + skof, (char*)As + 4096 + w * 1024);
        lds_stage16(BT + (size_t)(n0 + srow)      * K + k0 + skof, (char*)Bs + w * 1024);
        lds_stage16(BT + (size_t)(n0 + 64 + srow) * K + k0 + skof, (char*)Bs + 4096 + w * 1024);
        __syncthreads();  // drains vmcnt(0)

        bf16x8 af[4], bfr[4];
        #pragma unroll
        for (int i = 0; i < 4; i++) {
            af[i]  = *(const bf16x8*)&As[(wm + i * 16 + lr) * 32 + quad * 8];
            bfr[i] = *(const bf16x8*)&Bs[(wn + i * 16 + lr) * 32 + quad * 8];
        }
        #pragma unroll
        for (int i = 0; i < 4; i++)
            #pragma unroll
            for (int j = 0; j < 4; j++)
                acc[i][j] = mfma16(af[i], bfr[j], acc[i][j]);
    }
    // C/D layout: row = quad*4+r, col = lane&15 (m89/m91)
    #pragma unroll
    for (int i = 0; i < 4; i++)
        #pragma unroll
        for (int j = 0; j < 4; j++)
            #pragma unroll
            for (int r = 0; r < 4; r++) {
                int row = m0 + wm + i * 16 + quad * 4 + r;
                int col = n0 + wn + j * 16 + lr;
                float v = acc[i][j][r];
                if (scaleq && col < 1024) v *= 0.125f;  // fold 1/sqrt(64) into Q
                outB[(size_t)row * N + col] = f2bf(v);
            }
}

// ------------- GEMM 64x128 (for proj: 256 blocks) + residual epilogue -------------
__global__ __launch_bounds__(256) void gemm_bf16(
    const unsigned short* __restrict__ A,   // [M][K]
    const unsigned short* __restrict__ BT,  // [N][K]
    const float* __restrict__ res,          // [M][N] residual
    float* __restrict__ outF,               // fp32 out
    unsigned short* __restrict__ outB,      // bf16 out
    int M, int N, int K) {
    __shared__ __align__(16) unsigned short As[64 * 32];
    __shared__ __align__(16) unsigned short Bs[128 * 32];
    const int tid = threadIdx.x;
    const int m0 = blockIdx.y * 64, n0 = blockIdx.x * 128;
    const int w = tid >> 6, lane = tid & 63;
    const int wm = (w >> 1) * 32, wn = (w & 1) * 64;
    const int lr = lane & 15, quad = lane >> 4;
    const int loff = w * 1024 + lane * 16;
    const int srow = loff >> 6, skof = (loff & 63) >> 1;

    f32x4 acc[2][4] = {};

    for (int k0 = 0; k0 < K; k0 += 32) {
        __syncthreads();
        lds_stage16(A + (size_t)(m0 + srow) * K + k0 + skof, (char*)As + w * 1024);
        lds_stage16(BT + (size_t)(n0 + srow) * K + k0 + skof, (char*)Bs + w * 1024);
        lds_stage16(BT + (size_t)(n0 + 64 + srow) * K + k0 + skof,
                    (char*)Bs + 4096 + w * 1024);
        __syncthreads();

        bf16x8 af[2], bfr[4];
        #pragma unroll
        for (int i = 0; i < 2; i++)
            af[i] = *(const bf16x8*)&As[(wm + i * 16 + lr) * 32 + quad * 8];
        #pragma unroll
        for (int j = 0; j < 4; j++)
            bfr[j] = *(const bf16x8*)&Bs[(wn + j * 16 + lr) * 32 + quad * 8];
        #pragma unroll
        for (int i = 0; i < 2; i++)
            #pragma unroll
            for (int j = 0; j < 4; j++)
                acc[i][j] = mfma16(af[i], bfr[j], acc[i][j]);
    }
    #pragma unroll
    for (int i = 0; i < 2; i++)
        #pragma unroll
        for (int j = 0; j < 4; j++)
            #pragma unroll
            for (int r = 0; r < 4; r++) {
                int row = m0 + wm + i * 16 + quad * 4 + r;
                int col = n0 + wn + j * 16 + lr;
                float v = acc[i][j][r] + res[(size_t)row * N + col];
                if (outF) outF[(size_t)row * N + col] = v;
                if (outB) outB[(size_t)row * N + col] = f2bf(v);
            }
}

// ------------- V transpose: VT[bh][d][s] -------------
__global__ __launch_bounds__(256) void vtrans(
    const unsigned short* __restrict__ qkv, unsigned short* __restrict__ VT) {
    __shared__ unsigned short t[32][33];
    int bh = blockIdx.z, b = bh >> 4, h = bh & 15;
    int s0 = blockIdx.x * 32, d0 = blockIdx.y * 32;
    int tx = threadIdx.x & 31, ty = threadIdx.x >> 5;
    for (int i = ty; i < 32; i += 8)
        t[i][tx] = qkv[(size_t)(b * 1024 + s0 + i) * 3072 + 2048 + h * 64 + d0 + tx];
    __syncthreads();
    for (int i = ty; i < 32; i += 8)
        VT[((size_t)bh * 64 + d0 + i) * 1024 + s0 + tx] = t[tx][i];
}

// ------------- Flash attention, causal-balanced, KT=64, K-prefetch pipeline -------------
#define LOADK(KT, K0, K1)                                                      \
    {                                                                          \
        _Pragma("unroll")                                                      \
        for (int nh = 0; nh < 4; nh++) {                                       \
            const size_t rowK =                                                \
                (size_t)(b * 1024 + (KT) + nh * 16 + lr) * 3072 + 1024 + h * 64; \
            K0[nh] = *(const bf16x8*)&qkv[rowK + quad * 8];                    \
            K1[nh] = *(const bf16x8*)&qkv[rowK + 32 + quad * 8];               \
        }                                                                      \
    }

#define TILE_STEP(KT, KC0, KC1, KN0, KN1, PRE)                                 \
    {                                                                          \
        const int kt_ = (KT);                                                  \
        bf16x8 vb0[4], vb1[4];                                                 \
        _Pragma("unroll")                                                      \
        for (int dt = 0; dt < 4; dt++) {                                       \
            const size_t rowV = ((size_t)bh * 64 + dt * 16 + lr) * 1024 + kt_; \
            vb0[dt] = *(const bf16x8*)&VT[rowV + quad * 8];                    \
            vb1[dt] = *(const bf16x8*)&VT[rowV + 32 + quad * 8];               \
        }                                                                      \
        if (PRE) LOADK(kt_ + 64, KN0, KN1)                                     \
        f32x4 s[4] = {};                                                       \
        _Pragma("unroll")                                                      \
        for (int nh = 0; nh < 4; nh++) {                                       \
            s[nh] = mfma16(aq0, KC0[nh], s[nh]);                               \
            s[nh] = mfma16(aq1, KC1[nh], s[nh]);                               \
        }                                                                      \
        float mx[4];                                                           \
        _Pragma("unroll")                                                      \
        for (int r = 0; r < 4; r++) {                                          \
            int qrow = qb + quad * 4 + r;                                      \
            _Pragma("unroll")                                                  \
            for (int nh = 0; nh < 4; nh++) {                                   \
                int kcol = kt_ + nh * 16 + lr;                                 \
                s[nh][r] = (kcol <= qrow) ? s[nh][r] : -1e30f;                 \
            }                                                                  \
            mx[r] = fmaxf(fmaxf(s[0][r], s[1][r]), fmaxf(s[2][r], s[3][r]));   \
        }                                                                      \
        _Pragma("unroll")                                                      \
        for (int d = 1; d < 16; d <<= 1) {                                     \
            _Pragma("unroll")                                                  \
            for (int r = 0; r < 4; r++)                                        \
                mx[r] = fmaxf(mx[r], __shfl_xor(mx[r], d));                    \
        }                                                                      \
        float al[4], rs[4];                                                    \
        _Pragma("unroll")                                                      \
        for (int r = 0; r < 4; r++) {                                          \
            float mnew = fmaxf(m_i[r], mx[r]);                                 \
            al[r] = exp2f((m_i[r] - mnew) * LOG2E);                            \
            m_i[r] = mnew;                                                     \
            float lsum = 0.f;                                                  \
            _Pragma("unroll")                                                  \
            for (int nh = 0; nh < 4; nh++) {                                   \
                float p = exp2f((s[nh][r] - mnew) * LOG2E);                    \
                s[nh][r] = p;                                                  \
                lsum += p;                                                     \
            }                                                                  \
            rs[r] = lsum;                                                      \
        }                                                                      \
        _Pragma("unroll")                                                      \
        for (int d = 1; d < 16; d <<= 1) {                                     \
            _Pragma("unroll")                                                  \
            for (int r = 0; r < 4; r++) rs[r] += __shfl_xor(rs[r], d);         \
        }                                                                      \
        _Pragma("unroll")                                                      \
        for (int r = 0; r < 4; r++) l_i[r] = l_i[r] * al[r] + rs[r];           \
        _Pragma("unroll")                                                      \
        for (int dt = 0; dt < 4; dt++) {                                       \
            _Pragma("unroll")                                                  \
            for (int r = 0; r < 4; r++) oacc[dt][r] *= al[r];                  \
        }                                                                      \
        _Pragma("unroll")                                                      \
        for (int nh = 0; nh < 4; nh++) {                                       \
            _Pragma("unroll")                                                  \
            for (int r = 0; r < 4; r++)                                        \
                pl[w][(quad * 4 + r) * 72 + nh * 16 + lr] = f2bf(s[nh][r]);    \
        }                                                                      \
        bf16x8 ap0 = *(const bf16x8*)&pl[w][lr * 72 + quad * 8];               \
        bf16x8 ap1 = *(const bf16x8*)&pl[w][lr * 72 + 32 + quad * 8];          \
        _Pragma("unroll")                                                      \
        for (int dt = 0; dt < 4; dt++) {                                       \
            oacc[dt] = mfma16(ap0, vb0[dt], oacc[dt]);                         \
            oacc[dt] = mfma16(ap1, vb1[dt], oacc[dt]);                         \
        }                                                                      \
    }

__global__ __launch_bounds__(256) void attn_kernel(
    const unsigned short* __restrict__ qkv,  // [2048][3072]
    const unsigned short* __restrict__ VT,   // [32][64][1024]
    unsigned short* __restrict__ O) {        // [2048][1024]
    __shared__ __align__(16) unsigned short pl[4][16 * 72];
    const int tid = threadIdx.x;
    const int w = tid >> 6, lane = tid & 63;
    const int lr = lane & 15, quad = lane >> 4;
    const int bh = blockIdx.y, b = bh >> 4, h = bh & 15;
    const int t = blockIdx.x * 4 + w;  // 0..31
    const float LOG2E = 1.44269504f;

    #pragma unroll
    for (int pass = 0; pass < 2; pass++) {
        const int qb = (pass ? (63 - t) : t) * 16;
        const size_t rowQ = (size_t)(b * 1024 + qb + lr) * 3072 + h * 64;
        bf16x8 aq0 = *(const bf16x8*)&qkv[rowQ + quad * 8];
        bf16x8 aq1 = *(const bf16x8*)&qkv[rowQ + 32 + quad * 8];

        float m_i[4], l_i[4];
        f32x4 oacc[4] = {};
        #pragma unroll
        for (int r = 0; r < 4; r++) { m_i[r] = -1e30f; l_i[r] = 0.f; }

        const int nkt = (qb + 16 + 63) >> 6;

        bf16x8 kA0[4], kA1[4], kB0[4], kB1[4];
        LOADK(0, kA0, kA1)
        for (int kt64 = 0; kt64 < nkt; kt64 += 2) {
            TILE_STEP(kt64 << 6, kA0, kA1, kB0, kB1, (kt64 + 1 < nkt))
            if (kt64 + 1 < nkt)
                TILE_STEP((kt64 + 1) << 6, kB0, kB1, kA0, kA1, (kt64 + 2 < nkt))
        }
        #pragma unroll
        for (int dt = 0; dt < 4; dt++)
            #pragma unroll
            for (int r = 0; r < 4; r++) {
                int row = b * 1024 + qb + quad * 4 + r;
                int col = h * 64 + dt * 16 + lr;
                O[(size_t)row * 1024 + col] = f2bf(oacc[dt][r] / l_i[r]);
            }
    }
}

extern "C" void kernel_launch(void* const* d_in, const int* in_sizes, int n_in,
                              void* d_out, int out_size, void* d_ws, size_t ws_size,
                              hipStream_t stream) {
    const float* x     = (const float*)d_in[0];
    const float* Wqkv  = (const float*)d_in[1];
    const float* Aqkv  = (const float*)d_in[2];
    const float* Bqkv  = (const float*)d_in[3];
    const float* Wproj = (const float*)d_in[4];
    const float* Aproj = (const float*)d_in[5];
    const float* Bproj = (const float*)d_in[6];
    float* out = (float*)d_out;

    char* ws = (char*)d_ws;
    float* h_f32 = (float*)ws;                    ws += (size_t)2048 * 1024 * 4;
    unsigned short* h_bf   = (unsigned short*)ws; ws += (size_t)2048 * 1024 * 2;
    unsigned short* qkv_bf = (unsigned short*)ws; ws += (size_t)2048 * 3072 * 2;
    unsigned short* VT     = (unsigned short*)ws; ws += (size_t)32 * 64 * 1024 * 2;
    unsigned short* O_bf   = (unsigned short*)ws; ws += (size_t)2048 * 1024 * 2;
    unsigned short* WqT    = (unsigned short*)ws; ws += (size_t)3072 * 1024 * 2;
    unsigned short* WpT    = (unsigned short*)ws; ws += (size_t)1024 * 1024 * 2;

    hipMemcpyAsync(h_f32, x, (size_t)2048 * 1024 * 4, hipMemcpyDeviceToDevice, stream);
    f32_to_bf16_vec<<<2048, 256, 0, stream>>>((const float4*)x, (ushort4*)h_bf,
                                              2048 * 1024 / 4);

    for (int l = 0; l < 8; l++) {
        const float* Wq = Wqkv  + (size_t)l * 1024 * 3072;
        const float* Aq = Aqkv  + (size_t)l * 1024 * 16;
        const float* Bq = Bqkv  + (size_t)l * 16 * 3072;
        const float* Wp = Wproj + (size_t)l * 1024 * 1024;
        const float* Ap = Aproj + (size_t)l * 1024 * 16;
        const float* Bp = Bproj + (size_t)l * 16 * 1024;

        merge_T<<<dim3(24, 32), 256, 0, stream>>>(Wq, Aq, Bq, WqT, 3072);
        merge_T<<<dim3(8, 32), 256, 0, stream>>>(Wp, Ap, Bp, WpT, 1024);
        // qkv GEMM: Q columns pre-scaled by 1/8
        gemm_bf16_128<<<dim3(24, 16), 256, 0, stream>>>(h_bf, WqT, qkv_bf,
                                                        2048, 3072, 1024, 1);
        vtrans<<<dim3(32, 2, 32), 256, 0, stream>>>(qkv_bf, VT);
        attn_kernel<<<dim3(8, 32), 256, 0, stream>>>(qkv_bf, VT, O_bf);
        float* outF = (l == 7) ? out : h_f32;
        gemm_bf16<<<dim3(8, 32), 256, 0, stream>>>(O_bf, WpT, h_f32, outF, h_bf,
                                                   2048, 1024, 1024);
    }
}

// Round 5
// 911.684 us; speedup vs baseline: 1.5547x; 1.1181x over previous
//
#include <hip/hip_runtime.h>
#include <hip/hip_bf16.h>

// LoRA transformer: L=8, D=1024, H=16, HD=64, R=16, B=2, S=1024.
// bf16 MFMA everywhere, fp32 residual stream.
// R5: gemm1 = 128x128, BK=64 via two 32-K sub-buffers per barrier (half the
// drains); gemm2 = 64x64 BK=64 (512 blocks, 2/CU); attn softmax reductions
// via DPP row_ror (VALU) instead of ds_swizzle, lane-local l, diag-only mask.

typedef unsigned short ushort_t;
typedef __attribute__((ext_vector_type(8))) short bf16x8;
typedef __attribute__((ext_vector_type(4))) float f32x4;

__device__ __forceinline__ unsigned short f2bf(float f) {
    union { float f; unsigned int u; } x; x.f = f;
    unsigned int r = x.u + 0x7fffu + ((x.u >> 16) & 1u);  // RNE
    return (unsigned short)(r >> 16);
}

__device__ __forceinline__ f32x4 mfma16(bf16x8 a, bf16x8 b, f32x4 c) {
    return __builtin_amdgcn_mfma_f32_16x16x32_bf16(a, b, c, 0, 0, 0);
}

typedef const __attribute__((address_space(1))) unsigned int* gas_ptr;
typedef __attribute__((address_space(3))) unsigned int* las_ptr;
// async global->LDS, 16B/lane; LDS dest = wave-uniform base + lane*16 (m104/m108)
__device__ __forceinline__ void lds_stage16(const void* g, void* l) {
    __builtin_amdgcn_global_load_lds((gas_ptr)(unsigned long long)g,
                                     (las_ptr)(unsigned int)(unsigned long long)l,
                                     16, 0, 0);
}

// DPP 16-lane row reductions (row_ror:S = 0x120+S); DPP row == 16 lanes,
// matching the 16 score columns (lanes quad*16..quad*16+15).
#define RORMAX(x, C)                                                           \
    x = fmaxf(x, __int_as_float(__builtin_amdgcn_mov_dpp(                      \
                     __float_as_int(x), C, 0xf, 0xf, false)));
#define RORADD(x, C)                                                           \
    x += __int_as_float(__builtin_amdgcn_mov_dpp(                              \
        __float_as_int(x), C, 0xf, 0xf, false));

// ---------------- fp32 -> bf16 ----------------
__global__ __launch_bounds__(256) void f32_to_bf16_vec(
    const float4* __restrict__ in, ushort4* __restrict__ out, int n4) {
    int i = blockIdx.x * 256 + threadIdx.x;
    if (i < n4) {
        float4 v = in[i];
        ushort4 o;
        o.x = f2bf(v.x); o.y = f2bf(v.y); o.z = f2bf(v.z); o.w = f2bf(v.w);
        out[i] = o;
    }
}

// ------------- LoRA merge + transpose (vectorized) -------------
__global__ __launch_bounds__(256) void merge_T(
    const float* __restrict__ W, const float* __restrict__ A,
    const float* __restrict__ Bm, unsigned short* __restrict__ WT, int N) {
    __shared__ float t[32][132];
    int j0 = blockIdx.x * 128, i0 = blockIdx.y * 32;
    int tx = threadIdx.x & 31, ty = threadIdx.x >> 5;  // 32 x 8
    for (int ii = ty; ii < 32; ii += 8) {
        int i = i0 + ii;
        float4 acc = *(const float4*)&W[(size_t)i * N + j0 + tx * 4];
        #pragma unroll
        for (int r = 0; r < 16; r++) {
            float a = A[i * 16 + r];
            float4 bv = *(const float4*)&Bm[(size_t)r * N + j0 + tx * 4];
            acc.x += a * bv.x; acc.y += a * bv.y;
            acc.z += a * bv.z; acc.w += a * bv.w;
        }
        *(float4*)&t[ii][tx * 4] = acc;
    }
    __syncthreads();
    int jj = threadIdx.x >> 1, half = threadIdx.x & 1;
    bf16x8 o0, o1;
    #pragma unroll
    for (int c = 0; c < 8; c++) o0[c] = (short)f2bf(t[half * 16 + c][jj]);
    #pragma unroll
    for (int c = 0; c < 8; c++) o1[c] = (short)f2bf(t[half * 16 + 8 + c][jj]);
    unsigned short* dst = &WT[(size_t)(j0 + jj) * 1024 + i0 + half * 16];
    *(bf16x8*)dst = o0;
    *(bf16x8*)(dst + 8) = o1;
}

// ------------- GEMM 128x128, BK=64 (two m97-shape sub-buffers/barrier) -------------
__global__ __launch_bounds__(256) void gemm_bf16_128(
    const unsigned short* __restrict__ A,   // [M][K]
    const unsigned short* __restrict__ BT,  // [N][K]
    unsigned short* __restrict__ outB,      // bf16 out
    int M, int N, int K, int scaleq) {
    __shared__ __align__(16) unsigned short As[2][128 * 32];
    __shared__ __align__(16) unsigned short Bs[2][128 * 32];
    const int tid = threadIdx.x;
    const int m0 = blockIdx.y * 128, n0 = blockIdx.x * 128;
    const int w = tid >> 6, lane = tid & 63;
    const int wm = (w >> 1) * 64, wn = (w & 1) * 64;
    const int lr = lane & 15, quad = lane >> 4;
    const int srow = w * 16 + (lane >> 2);   // staging row within 64-row half
    const int skof = (lane & 3) * 8;         // ushort k-offset within 32

    f32x4 acc[4][4] = {};

    for (int k0 = 0; k0 < K; k0 += 64) {
        __syncthreads();
        #pragma unroll
        for (int h = 0; h < 2; h++) {
            lds_stage16(A  + (size_t)(m0 + srow)      * K + k0 + h * 32 + skof,
                        (char*)As[h] + w * 1024);
            lds_stage16(A  + (size_t)(m0 + 64 + srow) * K + k0 + h * 32 + skof,
                        (char*)As[h] + 4096 + w * 1024);
            lds_stage16(BT + (size_t)(n0 + srow)      * K + k0 + h * 32 + skof,
                        (char*)Bs[h] + w * 1024);
            lds_stage16(BT + (size_t)(n0 + 64 + srow) * K + k0 + h * 32 + skof,
                        (char*)Bs[h] + 4096 + w * 1024);
        }
        __syncthreads();  // drains vmcnt(0)

        #pragma unroll
        for (int h = 0; h < 2; h++) {
            bf16x8 af[4], bfr[4];
            #pragma unroll
            for (int i = 0; i < 4; i++) {
                af[i]  = *(const bf16x8*)&As[h][(wm + i * 16 + lr) * 32 + quad * 8];
                bfr[i] = *(const bf16x8*)&Bs[h][(wn + i * 16 + lr) * 32 + quad * 8];
            }
            #pragma unroll
            for (int i = 0; i < 4; i++)
                #pragma unroll
                for (int j = 0; j < 4; j++)
                    acc[i][j] = mfma16(af[i], bfr[j], acc[i][j]);
        }
    }
    // C/D layout: row = quad*4+r, col = lane&15 (m89/m91)
    #pragma unroll
    for (int i = 0; i < 4; i++)
        #pragma unroll
        for (int j = 0; j < 4; j++)
            #pragma unroll
            for (int r = 0; r < 4; r++) {
                int row = m0 + wm + i * 16 + quad * 4 + r;
                int col = n0 + wn + j * 16 + lr;
                float v = acc[i][j][r];
                if (scaleq && col < 1024) v *= 0.125f;  // fold 1/sqrt(64) into Q
                outB[(size_t)row * N + col] = f2bf(v);
            }
}

// ------------- GEMM 64x64, BK=64 (proj: 512 blocks, 2/CU) + residual -------------
__global__ __launch_bounds__(256) void gemm_bf16_64(
    const unsigned short* __restrict__ A,   // [M][K]
    const unsigned short* __restrict__ BT,  // [N][K]
    const float* __restrict__ res,          // [M][N] residual
    float* __restrict__ outF,               // fp32 out
    unsigned short* __restrict__ outB,      // bf16 out
    int M, int N, int K) {
    __shared__ __align__(16) unsigned short As[2][64 * 32];
    __shared__ __align__(16) unsigned short Bs[2][64 * 32];
    const int tid = threadIdx.x;
    const int m0 = blockIdx.y * 64, n0 = blockIdx.x * 64;
    const int w = tid >> 6, lane = tid & 63;
    const int wm = (w >> 1) * 32, wn = (w & 1) * 32;
    const int lr = lane & 15, quad = lane >> 4;
    const int srow = w * 16 + (lane >> 2);
    const int skof = (lane & 3) * 8;

    f32x4 acc[2][2] = {};

    for (int k0 = 0; k0 < K; k0 += 64) {
        __syncthreads();
        #pragma unroll
        for (int h = 0; h < 2; h++) {
            lds_stage16(A  + (size_t)(m0 + srow) * K + k0 + h * 32 + skof,
                        (char*)As[h] + w * 1024);
            lds_stage16(BT + (size_t)(n0 + srow) * K + k0 + h * 32 + skof,
                        (char*)Bs[h] + w * 1024);
        }
        __syncthreads();

        #pragma unroll
        for (int h = 0; h < 2; h++) {
            bf16x8 af[2], bfr[2];
            #pragma unroll
            for (int i = 0; i < 2; i++) {
                af[i]  = *(const bf16x8*)&As[h][(wm + i * 16 + lr) * 32 + quad * 8];
                bfr[i] = *(const bf16x8*)&Bs[h][(wn + i * 16 + lr) * 32 + quad * 8];
            }
            #pragma unroll
            for (int i = 0; i < 2; i++)
                #pragma unroll
                for (int j = 0; j < 2; j++)
                    acc[i][j] = mfma16(af[i], bfr[j], acc[i][j]);
        }
    }
    #pragma unroll
    for (int i = 0; i < 2; i++)
        #pragma unroll
        for (int j = 0; j < 2; j++)
            #pragma unroll
            for (int r = 0; r < 4; r++) {
                int row = m0 + wm + i * 16 + quad * 4 + r;
                int col = n0 + wn + j * 16 + lr;
                float v = acc[i][j][r] + res[(size_t)row * N + col];
                if (outF) outF[(size_t)row * N + col] = v;
                if (outB) outB[(size_t)row * N + col] = f2bf(v);
            }
}

// ------------- V transpose: VT[bh][d][s] -------------
__global__ __launch_bounds__(256) void vtrans(
    const unsigned short* __restrict__ qkv, unsigned short* __restrict__ VT) {
    __shared__ unsigned short t[32][33];
    int bh = blockIdx.z, b = bh >> 4, h = bh & 15;
    int s0 = blockIdx.x * 32, d0 = blockIdx.y * 32;
    int tx = threadIdx.x & 31, ty = threadIdx.x >> 5;
    for (int i = ty; i < 32; i += 8)
        t[i][tx] = qkv[(size_t)(b * 1024 + s0 + i) * 3072 + 2048 + h * 64 + d0 + tx];
    __syncthreads();
    for (int i = ty; i < 32; i += 8)
        VT[((size_t)bh * 64 + d0 + i) * 1024 + s0 + tx] = t[tx][i];
}

// ------------- Flash attention, causal-balanced, KT=64, K-prefetch pipeline -------------
#define LOADK(KT, K0, K1)                                                      \
    {                                                                          \
        _Pragma("unroll")                                                      \
        for (int nh = 0; nh < 4; nh++) {                                       \
            const size_t rowK =                                                \
                (size_t)(b * 1024 + (KT) + nh * 16 + lr) * 3072 + 1024 + h * 64; \
            K0[nh] = *(const bf16x8*)&qkv[rowK + quad * 8];                    \
            K1[nh] = *(const bf16x8*)&qkv[rowK + 32 + quad * 8];               \
        }                                                                      \
    }

#define TILE_STEP(KT, KC0, KC1, KN0, KN1, PRE)                                 \
    {                                                                          \
        const int kt_ = (KT);                                                  \
        bf16x8 vb0[4], vb1[4];                                                 \
        _Pragma("unroll")                                                      \
        for (int dt = 0; dt < 4; dt++) {                                       \
            const size_t rowV = ((size_t)bh * 64 + dt * 16 + lr) * 1024 + kt_; \
            vb0[dt] = *(const bf16x8*)&VT[rowV + quad * 8];                    \
            vb1[dt] = *(const bf16x8*)&VT[rowV + 32 + quad * 8];               \
        }                                                                      \
        if (PRE) LOADK(kt_ + 64, KN0, KN1)                                     \
        f32x4 s[4] = {};                                                       \
        _Pragma("unroll")                                                      \
        for (int nh = 0; nh < 4; nh++) {                                       \
            s[nh] = mfma16(aq0, KC0[nh], s[nh]);                               \
            s[nh] = mfma16(aq1, KC1[nh], s[nh]);                               \
        }                                                                      \
        float mx[4];                                                           \
        if (kt_ + 64 > qb) { /* diagonal tile: apply causal mask */            \
            _Pragma("unroll")                                                  \
            for (int r = 0; r < 4; r++) {                                      \
                int qrow = qb + quad * 4 + r;                                  \
                _Pragma("unroll")                                              \
                for (int nh = 0; nh < 4; nh++) {                               \
                    int kcol = kt_ + nh * 16 + lr;                             \
                    s[nh][r] = (kcol <= qrow) ? s[nh][r] : -1e30f;             \
                }                                                              \
            }                                                                  \
        }                                                                      \
        _Pragma("unroll")                                                      \
        for (int r = 0; r < 4; r++) {                                          \
            mx[r] = fmaxf(fmaxf(s[0][r], s[1][r]), fmaxf(s[2][r], s[3][r]));   \
            RORMAX(mx[r], 0x121) RORMAX(mx[r], 0x122)                          \
            RORMAX(mx[r], 0x124) RORMAX(mx[r], 0x128)                          \
        }                                                                      \
        float al[4];                                                           \
        _Pragma("unroll")                                                      \
        for (int r = 0; r < 4; r++) {                                          \
            float mnew = fmaxf(m_i[r], mx[r]);                                 \
            al[r] = exp2f((m_i[r] - mnew) * LOG2E);                            \
            m_i[r] = mnew;                                                     \
            float lsum = 0.f;                                                  \
            _Pragma("unroll")                                                  \
            for (int nh = 0; nh < 4; nh++) {                                   \
                float p = exp2f((s[nh][r] - mnew) * LOG2E);                    \
                s[nh][r] = p;                                                  \
                lsum += p;                                                     \
            }                                                                  \
            l_i[r] = l_i[r] * al[r] + lsum; /* lane-local partial sum */       \
        }                                                                      \
        _Pragma("unroll")                                                      \
        for (int dt = 0; dt < 4; dt++) {                                       \
            _Pragma("unroll")                                                  \
            for (int r = 0; r < 4; r++) oacc[dt][r] *= al[r];                  \
        }                                                                      \
        _Pragma("unroll")                                                      \
        for (int nh = 0; nh < 4; nh++) {                                       \
            _Pragma("unroll")                                                  \
            for (int r = 0; r < 4; r++)                                        \
                pl[w][(quad * 4 + r) * 72 + nh * 16 + lr] = f2bf(s[nh][r]);    \
        }                                                                      \
        bf16x8 ap0 = *(const bf16x8*)&pl[w][lr * 72 + quad * 8];               \
        bf16x8 ap1 = *(const bf16x8*)&pl[w][lr * 72 + 32 + quad * 8];          \
        _Pragma("unroll")                                                      \
        for (int dt = 0; dt < 4; dt++) {                                       \
            oacc[dt] = mfma16(ap0, vb0[dt], oacc[dt]);                         \
            oacc[dt] = mfma16(ap1, vb1[dt], oacc[dt]);                         \
        }                                                                      \
    }

__global__ __launch_bounds__(256) void attn_kernel(
    const unsigned short* __restrict__ qkv,  // [2048][3072]
    const unsigned short* __restrict__ VT,   // [32][64][1024]
    unsigned short* __restrict__ O) {        // [2048][1024]
    __shared__ __align__(16) unsigned short pl[4][16 * 72];
    const int tid = threadIdx.x;
    const int w = tid >> 6, lane = tid & 63;
    const int lr = lane & 15, quad = lane >> 4;
    const int bh = blockIdx.y, b = bh >> 4, h = bh & 15;
    const int t = blockIdx.x * 4 + w;  // 0..31
    const float LOG2E = 1.44269504f;

    #pragma unroll
    for (int pass = 0; pass < 2; pass++) {
        const int qb = (pass ? (63 - t) : t) * 16;
        const size_t rowQ = (size_t)(b * 1024 + qb + lr) * 3072 + h * 64;
        bf16x8 aq0 = *(const bf16x8*)&qkv[rowQ + quad * 8];
        bf16x8 aq1 = *(const bf16x8*)&qkv[rowQ + 32 + quad * 8];

        float m_i[4], l_i[4];
        f32x4 oacc[4] = {};
        #pragma unroll
        for (int r = 0; r < 4; r++) { m_i[r] = -1e30f; l_i[r] = 0.f; }

        const int nkt = (qb + 16 + 63) >> 6;

        bf16x8 kA0[4], kA1[4], kB0[4], kB1[4];
        LOADK(0, kA0, kA1)
        for (int kt64 = 0; kt64 < nkt; kt64 += 2) {
            TILE_STEP(kt64 << 6, kA0, kA1, kB0, kB1, (kt64 + 1 < nkt))
            if (kt64 + 1 < nkt)
                TILE_STEP((kt64 + 1) << 6, kB0, kB1, kA0, kA1, (kt64 + 2 < nkt))
        }
        // cross-lane finish of l (16 col-lanes per row group)
        #pragma unroll
        for (int r = 0; r < 4; r++) {
            RORADD(l_i[r], 0x121) RORADD(l_i[r], 0x122)
            RORADD(l_i[r], 0x124) RORADD(l_i[r], 0x128)
        }
        #pragma unroll
        for (int dt = 0; dt < 4; dt++)
            #pragma unroll
            for (int r = 0; r < 4; r++) {
                int row = b * 1024 + qb + quad * 4 + r;
                int col = h * 64 + dt * 16 + lr;
                O[(size_t)row * 1024 + col] = f2bf(oacc[dt][r] / l_i[r]);
            }
    }
}

extern "C" void kernel_launch(void* const* d_in, const int* in_sizes, int n_in,
                              void* d_out, int out_size, void* d_ws, size_t ws_size,
                              hipStream_t stream) {
    const float* x     = (const float*)d_in[0];
    const float* Wqkv  = (const float*)d_in[1];
    const float* Aqkv  = (const float*)d_in[2];
    const float* Bqkv  = (const float*)d_in[3];
    const float* Wproj = (const float*)d_in[4];
    const float* Aproj = (const float*)d_in[5];
    const float* Bproj = (const float*)d_in[6];
    float* out = (float*)d_out;

    char* ws = (char*)d_ws;
    float* h_f32 = (float*)ws;                    ws += (size_t)2048 * 1024 * 4;
    unsigned short* h_bf   = (unsigned short*)ws; ws += (size_t)2048 * 1024 * 2;
    unsigned short* qkv_bf = (unsigned short*)ws; ws += (size_t)2048 * 3072 * 2;
    unsigned short* VT     = (unsigned short*)ws; ws += (size_t)32 * 64 * 1024 * 2;
    unsigned short* O_bf   = (unsigned short*)ws; ws += (size_t)2048 * 1024 * 2;
    unsigned short* WqT    = (unsigned short*)ws; ws += (size_t)3072 * 1024 * 2;
    unsigned short* WpT    = (unsigned short*)ws; ws += (size_t)1024 * 1024 * 2;

    hipMemcpyAsync(h_f32, x, (size_t)2048 * 1024 * 4, hipMemcpyDeviceToDevice, stream);
    f32_to_bf16_vec<<<2048, 256, 0, stream>>>((const float4*)x, (ushort4*)h_bf,
                                              2048 * 1024 / 4);

    for (int l = 0; l < 8; l++) {
        const float* Wq = Wqkv  + (size_t)l * 1024 * 3072;
        const float* Aq = Aqkv  + (size_t)l * 1024 * 16;
        const float* Bq = Bqkv  + (size_t)l * 16 * 3072;
        const float* Wp = Wproj + (size_t)l * 1024 * 1024;
        const float* Ap = Aproj + (size_t)l * 1024 * 16;
        const float* Bp = Bproj + (size_t)l * 16 * 1024;

        merge_T<<<dim3(24, 32), 256, 0, stream>>>(Wq, Aq, Bq, WqT, 3072);
        merge_T<<<dim3(8, 32), 256, 0, stream>>>(Wp, Ap, Bp, WpT, 1024);
        // qkv GEMM: Q columns pre-scaled by 1/8
        gemm_bf16_128<<<dim3(24, 16), 256, 0, stream>>>(h_bf, WqT, qkv_bf,
                                                        2048, 3072, 1024, 1);
        vtrans<<<dim3(32, 2, 32), 256, 0, stream>>>(qkv_bf, VT);
        attn_kernel<<<dim3(8, 32), 256, 0, stream>>>(qkv_bf, VT, O_bf);
        float* outF = (l == 7) ? out : h_f32;
        gemm_bf16_64<<<dim3(16, 32), 256, 0, stream>>>(O_bf, WpT, h_f32, outF,
                                                       h_bf, 2048, 1024, 1024);
    }
}

// Round 6
// 877.382 us; speedup vs baseline: 1.6155x; 1.0391x over previous
//
#include <hip/hip_runtime.h>
#include <hip/hip_bf16.h>

// LoRA transformer: L=8, D=1024, H=16, HD=64, R=16, B=2, S=1024.
// bf16 MFMA everywhere, fp32 residual stream.
// R6: attention rebuilt on the m97 GEMM skeleton — K/V staged to LDS via
// global_load_lds (64B rows), 4 waves share a 64-row Q-block, in-block
// causal pairing (t, 15-t) -> 17 uniform k-steps/block. Fixes R5's
// register-serialized K/V loads (VGPR 108, 9k cyc/k-step).

typedef unsigned short ushort_t;
typedef __attribute__((ext_vector_type(8))) short bf16x8;
typedef __attribute__((ext_vector_type(4))) float f32x4;

__device__ __forceinline__ unsigned short f2bf(float f) {
    union { float f; unsigned int u; } x; x.f = f;
    unsigned int r = x.u + 0x7fffu + ((x.u >> 16) & 1u);  // RNE
    return (unsigned short)(r >> 16);
}

__device__ __forceinline__ f32x4 mfma16(bf16x8 a, bf16x8 b, f32x4 c) {
    return __builtin_amdgcn_mfma_f32_16x16x32_bf16(a, b, c, 0, 0, 0);
}

typedef const __attribute__((address_space(1))) unsigned int* gas_ptr;
typedef __attribute__((address_space(3))) unsigned int* las_ptr;
// async global->LDS, 16B/lane; LDS dest = wave-uniform base + lane*16 (m104/m108)
__device__ __forceinline__ void lds_stage16(const void* g, void* l) {
    __builtin_amdgcn_global_load_lds((gas_ptr)(unsigned long long)g,
                                     (las_ptr)(unsigned int)(unsigned long long)l,
                                     16, 0, 0);
}

// DPP 16-lane row reductions (row_ror:S = 0x120+S)
#define RORMAX(x, C)                                                           \
    x = fmaxf(x, __int_as_float(__builtin_amdgcn_mov_dpp(                      \
                     __float_as_int(x), C, 0xf, 0xf, false)));
#define RORADD(x, C)                                                           \
    x += __int_as_float(__builtin_amdgcn_mov_dpp(                              \
        __float_as_int(x), C, 0xf, 0xf, false));

// ---------------- fp32 -> bf16 ----------------
__global__ __launch_bounds__(256) void f32_to_bf16_vec(
    const float4* __restrict__ in, ushort4* __restrict__ out, int n4) {
    int i = blockIdx.x * 256 + threadIdx.x;
    if (i < n4) {
        float4 v = in[i];
        ushort4 o;
        o.x = f2bf(v.x); o.y = f2bf(v.y); o.z = f2bf(v.z); o.w = f2bf(v.w);
        out[i] = o;
    }
}

// ------------- LoRA merge + transpose (vectorized) -------------
__global__ __launch_bounds__(256) void merge_T(
    const float* __restrict__ W, const float* __restrict__ A,
    const float* __restrict__ Bm, unsigned short* __restrict__ WT, int N) {
    __shared__ float t[32][132];
    int j0 = blockIdx.x * 128, i0 = blockIdx.y * 32;
    int tx = threadIdx.x & 31, ty = threadIdx.x >> 5;  // 32 x 8
    for (int ii = ty; ii < 32; ii += 8) {
        int i = i0 + ii;
        float4 acc = *(const float4*)&W[(size_t)i * N + j0 + tx * 4];
        #pragma unroll
        for (int r = 0; r < 16; r++) {
            float a = A[i * 16 + r];
            float4 bv = *(const float4*)&Bm[(size_t)r * N + j0 + tx * 4];
            acc.x += a * bv.x; acc.y += a * bv.y;
            acc.z += a * bv.z; acc.w += a * bv.w;
        }
        *(float4*)&t[ii][tx * 4] = acc;
    }
    __syncthreads();
    int jj = threadIdx.x >> 1, half = threadIdx.x & 1;
    bf16x8 o0, o1;
    #pragma unroll
    for (int c = 0; c < 8; c++) o0[c] = (short)f2bf(t[half * 16 + c][jj]);
    #pragma unroll
    for (int c = 0; c < 8; c++) o1[c] = (short)f2bf(t[half * 16 + 8 + c][jj]);
    unsigned short* dst = &WT[(size_t)(j0 + jj) * 1024 + i0 + half * 16];
    *(bf16x8*)dst = o0;
    *(bf16x8*)(dst + 8) = o1;
}

// ------------- GEMM 128x128, BK=64 (two m97-shape sub-buffers/barrier) -------------
__global__ __launch_bounds__(256) void gemm_bf16_128(
    const unsigned short* __restrict__ A,   // [M][K]
    const unsigned short* __restrict__ BT,  // [N][K]
    unsigned short* __restrict__ outB,      // bf16 out
    int M, int N, int K, int scaleq) {
    __shared__ __align__(16) unsigned short As[2][128 * 32];
    __shared__ __align__(16) unsigned short Bs[2][128 * 32];
    const int tid = threadIdx.x;
    const int m0 = blockIdx.y * 128, n0 = blockIdx.x * 128;
    const int w = tid >> 6, lane = tid & 63;
    const int wm = (w >> 1) * 64, wn = (w & 1) * 64;
    const int lr = lane & 15, quad = lane >> 4;
    const int srow = w * 16 + (lane >> 2);
    const int skof = (lane & 3) * 8;

    f32x4 acc[4][4] = {};

    for (int k0 = 0; k0 < K; k0 += 64) {
        __syncthreads();
        #pragma unroll
        for (int h = 0; h < 2; h++) {
            lds_stage16(A  + (size_t)(m0 + srow)      * K + k0 + h * 32 + skof,
                        (char*)As[h] + w * 1024);
            lds_stage16(A  + (size_t)(m0 + 64 + srow) * K + k0 + h * 32 + skof,
                        (char*)As[h] + 4096 + w * 1024);
            lds_stage16(BT + (size_t)(n0 + srow)      * K + k0 + h * 32 + skof,
                        (char*)Bs[h] + w * 1024);
            lds_stage16(BT + (size_t)(n0 + 64 + srow) * K + k0 + h * 32 + skof,
                        (char*)Bs[h] + 4096 + w * 1024);
        }
        __syncthreads();

        #pragma unroll
        for (int h = 0; h < 2; h++) {
            bf16x8 af[4], bfr[4];
            #pragma unroll
            for (int i = 0; i < 4; i++) {
                af[i]  = *(const bf16x8*)&As[h][(wm + i * 16 + lr) * 32 + quad * 8];
                bfr[i] = *(const bf16x8*)&Bs[h][(wn + i * 16 + lr) * 32 + quad * 8];
            }
            #pragma unroll
            for (int i = 0; i < 4; i++)
                #pragma unroll
                for (int j = 0; j < 4; j++)
                    acc[i][j] = mfma16(af[i], bfr[j], acc[i][j]);
        }
    }
    #pragma unroll
    for (int i = 0; i < 4; i++)
        #pragma unroll
        for (int j = 0; j < 4; j++)
            #pragma unroll
            for (int r = 0; r < 4; r++) {
                int row = m0 + wm + i * 16 + quad * 4 + r;
                int col = n0 + wn + j * 16 + lr;
                float v = acc[i][j][r];
                if (scaleq && col < 1024) v *= 0.125f;
                outB[(size_t)row * N + col] = f2bf(v);
            }
}

// ------------- GEMM 64x64, BK=64 (proj: 512 blocks, 2/CU) + residual -------------
__global__ __launch_bounds__(256) void gemm_bf16_64(
    const unsigned short* __restrict__ A,   // [M][K]
    const unsigned short* __restrict__ BT,  // [N][K]
    const float* __restrict__ res,          // [M][N] residual
    float* __restrict__ outF,               // fp32 out
    unsigned short* __restrict__ outB,      // bf16 out
    int M, int N, int K) {
    __shared__ __align__(16) unsigned short As[2][64 * 32];
    __shared__ __align__(16) unsigned short Bs[2][64 * 32];
    const int tid = threadIdx.x;
    const int m0 = blockIdx.y * 64, n0 = blockIdx.x * 64;
    const int w = tid >> 6, lane = tid & 63;
    const int wm = (w >> 1) * 32, wn = (w & 1) * 32;
    const int lr = lane & 15, quad = lane >> 4;
    const int srow = w * 16 + (lane >> 2);
    const int skof = (lane & 3) * 8;

    f32x4 acc[2][2] = {};

    for (int k0 = 0; k0 < K; k0 += 64) {
        __syncthreads();
        #pragma unroll
        for (int h = 0; h < 2; h++) {
            lds_stage16(A  + (size_t)(m0 + srow) * K + k0 + h * 32 + skof,
                        (char*)As[h] + w * 1024);
            lds_stage16(BT + (size_t)(n0 + srow) * K + k0 + h * 32 + skof,
                        (char*)Bs[h] + w * 1024);
        }
        __syncthreads();

        #pragma unroll
        for (int h = 0; h < 2; h++) {
            bf16x8 af[2], bfr[2];
            #pragma unroll
            for (int i = 0; i < 2; i++) {
                af[i]  = *(const bf16x8*)&As[h][(wm + i * 16 + lr) * 32 + quad * 8];
                bfr[i] = *(const bf16x8*)&Bs[h][(wn + i * 16 + lr) * 32 + quad * 8];
            }
            #pragma unroll
            for (int i = 0; i < 2; i++)
                #pragma unroll
                for (int j = 0; j < 2; j++)
                    acc[i][j] = mfma16(af[i], bfr[j], acc[i][j]);
        }
    }
    #pragma unroll
    for (int i = 0; i < 2; i++)
        #pragma unroll
        for (int j = 0; j < 2; j++)
            #pragma unroll
            for (int r = 0; r < 4; r++) {
                int row = m0 + wm + i * 16 + quad * 4 + r;
                int col = n0 + wn + j * 16 + lr;
                float v = acc[i][j][r] + res[(size_t)row * N + col];
                if (outF) outF[(size_t)row * N + col] = v;
                if (outB) outB[(size_t)row * N + col] = f2bf(v);
            }
}

// ------------- V transpose: VT[bh][d][s] -------------
__global__ __launch_bounds__(256) void vtrans(
    const unsigned short* __restrict__ qkv, unsigned short* __restrict__ VT) {
    __shared__ unsigned short t[32][33];
    int bh = blockIdx.z, b = bh >> 4, h = bh & 15;
    int s0 = blockIdx.x * 32, d0 = blockIdx.y * 32;
    int tx = threadIdx.x & 31, ty = threadIdx.x >> 5;
    for (int i = ty; i < 32; i += 8)
        t[i][tx] = qkv[(size_t)(b * 1024 + s0 + i) * 3072 + 2048 + h * 64 + d0 + tx];
    __syncthreads();
    for (int i = ty; i < 32; i += 8)
        VT[((size_t)bh * 64 + d0 + i) * 1024 + s0 + tx] = t[tx][i];
}

// ------------- Flash attention: LDS-staged K/V, 4 waves share a 64-row Q-block -------------
// Grid (8, 32): block processes q-blocks t and 15-t of its (b,h) -> 17 k-steps
// total, uniform across all 256 blocks. K/V tiles (64x64) staged via
// global_load_lds into m97-shape [2][64x32] buffers (64B rows).
__global__ __launch_bounds__(256) void attn_kernel(
    const unsigned short* __restrict__ qkv,  // [2048][3072]
    const unsigned short* __restrict__ VT,   // [32][64][1024]
    unsigned short* __restrict__ O) {        // [2048][1024]
    __shared__ __align__(16) unsigned short Ks[2][64 * 32];  // [dhalf][s][d32]
    __shared__ __align__(16) unsigned short Vs[2][64 * 32];  // [shalf][d][s32]
    __shared__ __align__(16) unsigned short pl[4][16 * 72];
    const int tid = threadIdx.x;
    const int w = tid >> 6, lane = tid & 63;
    const int lr = lane & 15, quad = lane >> 4;
    const int bh = blockIdx.y, b = bh >> 4, h = bh & 15;
    const int srow = w * 16 + (lane >> 2);   // staging row 0..63
    const int skof = (lane & 3) * 8;         // staging ushort offset 0..24
    const float LOG2E = 1.44269504f;

    #pragma unroll
    for (int pass = 0; pass < 2; pass++) {
        const int qblk = pass ? (15 - blockIdx.x) : blockIdx.x;  // 0..15
        const int qb = qblk * 64 + w * 16;   // wave's 16 q-rows
        const size_t rowQ = (size_t)(b * 1024 + qb + lr) * 3072 + h * 64;
        bf16x8 aq0 = *(const bf16x8*)&qkv[rowQ + quad * 8];
        bf16x8 aq1 = *(const bf16x8*)&qkv[rowQ + 32 + quad * 8];

        float m_i[4], l_i[4];
        f32x4 oacc[4] = {};
        #pragma unroll
        for (int r = 0; r < 4; r++) { m_i[r] = -1e30f; l_i[r] = 0.f; }

        const int nkt = qblk + 1;  // k-tiles of 64
        for (int kt64 = 0; kt64 < nkt; kt64++) {
            const int kt = kt64 << 6;
            __syncthreads();  // prev step's frag reads done
            // K tile: rows s (kt+srow), d halves 0..31 / 32..63
            const size_t gK = (size_t)(b * 1024 + kt + srow) * 3072 + 1024 + h * 64;
            lds_stage16(qkv + gK + skof,      (char*)Ks[0] + w * 1024);
            lds_stage16(qkv + gK + 32 + skof, (char*)Ks[1] + w * 1024);
            // V^T tile: rows d (srow), s halves kt+0..31 / kt+32..63
            const size_t gV = ((size_t)bh * 64 + srow) * 1024 + kt;
            lds_stage16(VT + gV + skof,       (char*)Vs[0] + w * 1024);
            lds_stage16(VT + gV + 32 + skof,  (char*)Vs[1] + w * 1024);
            __syncthreads();  // drains vmcnt(0)

            // QK^T: 16 q-rows x 64 k-cols
            f32x4 s[4] = {};
            #pragma unroll
            for (int nh = 0; nh < 4; nh++) {
                bf16x8 kb0 = *(const bf16x8*)&Ks[0][(nh * 16 + lr) * 32 + quad * 8];
                bf16x8 kb1 = *(const bf16x8*)&Ks[1][(nh * 16 + lr) * 32 + quad * 8];
                s[nh] = mfma16(aq0, kb0, s[nh]);
                s[nh] = mfma16(aq1, kb1, s[nh]);
            }
            float mx[4];
            if (kt + 64 > qb) {  // diagonal tile: causal mask
                #pragma unroll
                for (int r = 0; r < 4; r++) {
                    int qrow = qb + quad * 4 + r;
                    #pragma unroll
                    for (int nh = 0; nh < 4; nh++) {
                        int kcol = kt + nh * 16 + lr;
                        s[nh][r] = (kcol <= qrow) ? s[nh][r] : -1e30f;
                    }
                }
            }
            #pragma unroll
            for (int r = 0; r < 4; r++) {
                mx[r] = fmaxf(fmaxf(s[0][r], s[1][r]), fmaxf(s[2][r], s[3][r]));
                RORMAX(mx[r], 0x121) RORMAX(mx[r], 0x122)
                RORMAX(mx[r], 0x124) RORMAX(mx[r], 0x128)
            }
            float al[4];
            #pragma unroll
            for (int r = 0; r < 4; r++) {
                float mnew = fmaxf(m_i[r], mx[r]);
                al[r] = exp2f((m_i[r] - mnew) * LOG2E);
                m_i[r] = mnew;
                float lsum = 0.f;
                #pragma unroll
                for (int nh = 0; nh < 4; nh++) {
                    float p = exp2f((s[nh][r] - mnew) * LOG2E);
                    s[nh][r] = p;
                    lsum += p;
                }
                l_i[r] = l_i[r] * al[r] + lsum;  // lane-local partial
            }
            #pragma unroll
            for (int dt = 0; dt < 4; dt++)
                #pragma unroll
                for (int r = 0; r < 4; r++) oacc[dt][r] *= al[r];
            // P: C-layout -> LDS -> A-layout (wave-internal)
            #pragma unroll
            for (int nh = 0; nh < 4; nh++)
                #pragma unroll
                for (int r = 0; r < 4; r++)
                    pl[w][(quad * 4 + r) * 72 + nh * 16 + lr] = f2bf(s[nh][r]);
            bf16x8 ap0 = *(const bf16x8*)&pl[w][lr * 72 + quad * 8];
            bf16x8 ap1 = *(const bf16x8*)&pl[w][lr * 72 + 32 + quad * 8];
            #pragma unroll
            for (int dt = 0; dt < 4; dt++) {
                bf16x8 vb0 = *(const bf16x8*)&Vs[0][(dt * 16 + lr) * 32 + quad * 8];
                bf16x8 vb1 = *(const bf16x8*)&Vs[1][(dt * 16 + lr) * 32 + quad * 8];
                oacc[dt] = mfma16(ap0, vb0, oacc[dt]);
                oacc[dt] = mfma16(ap1, vb1, oacc[dt]);
            }
        }
        // cross-lane finish of l (16 col-lanes per row group)
        #pragma unroll
        for (int r = 0; r < 4; r++) {
            RORADD(l_i[r], 0x121) RORADD(l_i[r], 0x122)
            RORADD(l_i[r], 0x124) RORADD(l_i[r], 0x128)
        }
        #pragma unroll
        for (int dt = 0; dt < 4; dt++)
            #pragma unroll
            for (int r = 0; r < 4; r++) {
                int row = b * 1024 + qb + quad * 4 + r;
                int col = h * 64 + dt * 16 + lr;
                O[(size_t)row * 1024 + col] = f2bf(oacc[dt][r] / l_i[r]);
            }
        __syncthreads();  // all waves done with Ks/Vs before next pass restages
    }
}

extern "C" void kernel_launch(void* const* d_in, const int* in_sizes, int n_in,
                              void* d_out, int out_size, void* d_ws, size_t ws_size,
                              hipStream_t stream) {
    const float* x     = (const float*)d_in[0];
    const float* Wqkv  = (const float*)d_in[1];
    const float* Aqkv  = (const float*)d_in[2];
    const float* Bqkv  = (const float*)d_in[3];
    const float* Wproj = (const float*)d_in[4];
    const float* Aproj = (const float*)d_in[5];
    const float* Bproj = (const float*)d_in[6];
    float* out = (float*)d_out;

    char* ws = (char*)d_ws;
    float* h_f32 = (float*)ws;                    ws += (size_t)2048 * 1024 * 4;
    unsigned short* h_bf   = (unsigned short*)ws; ws += (size_t)2048 * 1024 * 2;
    unsigned short* qkv_bf = (unsigned short*)ws; ws += (size_t)2048 * 3072 * 2;
    unsigned short* VT     = (unsigned short*)ws; ws += (size_t)32 * 64 * 1024 * 2;
    unsigned short* O_bf   = (unsigned short*)ws; ws += (size_t)2048 * 1024 * 2;
    unsigned short* WqT    = (unsigned short*)ws; ws += (size_t)3072 * 1024 * 2;
    unsigned short* WpT    = (unsigned short*)ws; ws += (size_t)1024 * 1024 * 2;

    hipMemcpyAsync(h_f32, x, (size_t)2048 * 1024 * 4, hipMemcpyDeviceToDevice, stream);
    f32_to_bf16_vec<<<2048, 256, 0, stream>>>((const float4*)x, (ushort4*)h_bf,
                                              2048 * 1024 / 4);

    for (int l = 0; l < 8; l++) {
        const float* Wq = Wqkv  + (size_t)l * 1024 * 3072;
        const float* Aq = Aqkv  + (size_t)l * 1024 * 16;
        const float* Bq = Bqkv  + (size_t)l * 16 * 3072;
        const float* Wp = Wproj + (size_t)l * 1024 * 1024;
        const float* Ap = Aproj + (size_t)l * 1024 * 16;
        const float* Bp = Bproj + (size_t)l * 16 * 1024;

        merge_T<<<dim3(24, 32), 256, 0, stream>>>(Wq, Aq, Bq, WqT, 3072);
        merge_T<<<dim3(8, 32), 256, 0, stream>>>(Wp, Ap, Bp, WpT, 1024);
        // qkv GEMM: Q columns pre-scaled by 1/8
        gemm_bf16_128<<<dim3(24, 16), 256, 0, stream>>>(h_bf, WqT, qkv_bf,
                                                        2048, 3072, 1024, 1);
        vtrans<<<dim3(32, 2, 32), 256, 0, stream>>>(qkv_bf, VT);
        attn_kernel<<<dim3(8, 32), 256, 0, stream>>>(qkv_bf, VT, O_bf);
        float* outF = (l == 7) ? out : h_f32;
        gemm_bf16_64<<<dim3(16, 32), 256, 0, stream>>>(O_bf, WpT, h_f32, outF,
                                                       h_bf, 2048, 1024, 1024);
    }
}

// Round 7
// 809.781 us; speedup vs baseline: 1.7504x; 1.0835x over previous
//
#include <hip/hip_runtime.h>
#include <hip/hip_bf16.h>

// LoRA transformer: L=8, D=1024, H=16, HD=64, R=16, B=2, S=1024.
// bf16 MFMA everywhere, fp32 residual stream.
// R7: attn -> 512 blocks (2 waves/SIMD; one 64-row q-block each, complementary
// load mapping qblk = bh<16 ? x : 15-x); merge_T batched over all 8 layers
// (2 dispatches, gridDim.z=8); convert fused with residual-copy.

typedef unsigned short ushort_t;
typedef __attribute__((ext_vector_type(8))) short bf16x8;
typedef __attribute__((ext_vector_type(4))) float f32x4;

__device__ __forceinline__ unsigned short f2bf(float f) {
    union { float f; unsigned int u; } x; x.f = f;
    unsigned int r = x.u + 0x7fffu + ((x.u >> 16) & 1u);  // RNE
    return (unsigned short)(r >> 16);
}

__device__ __forceinline__ f32x4 mfma16(bf16x8 a, bf16x8 b, f32x4 c) {
    return __builtin_amdgcn_mfma_f32_16x16x32_bf16(a, b, c, 0, 0, 0);
}

typedef const __attribute__((address_space(1))) unsigned int* gas_ptr;
typedef __attribute__((address_space(3))) unsigned int* las_ptr;
// async global->LDS, 16B/lane; LDS dest = wave-uniform base + lane*16 (m104/m108)
__device__ __forceinline__ void lds_stage16(const void* g, void* l) {
    __builtin_amdgcn_global_load_lds((gas_ptr)(unsigned long long)g,
                                     (las_ptr)(unsigned int)(unsigned long long)l,
                                     16, 0, 0);
}

// DPP 16-lane row reductions (row_ror:S = 0x120+S)
#define RORMAX(x, C)                                                           \
    x = fmaxf(x, __int_as_float(__builtin_amdgcn_mov_dpp(                      \
                     __float_as_int(x), C, 0xf, 0xf, false)));
#define RORADD(x, C)                                                           \
    x += __int_as_float(__builtin_amdgcn_mov_dpp(                              \
        __float_as_int(x), C, 0xf, 0xf, false));

// ---------------- x -> (h_f32 copy, h_bf16) ----------------
__global__ __launch_bounds__(256) void convert_x(
    const float4* __restrict__ in, float4* __restrict__ outF,
    ushort4* __restrict__ outB, int n4) {
    int i = blockIdx.x * 256 + threadIdx.x;
    if (i < n4) {
        float4 v = in[i];
        outF[i] = v;
        ushort4 o;
        o.x = f2bf(v.x); o.y = f2bf(v.y); o.z = f2bf(v.z); o.w = f2bf(v.w);
        outB[i] = o;
    }
}

// ------------- LoRA merge + transpose, batched over layers (z) -------------
// WT[z][n][k] = bf16(W[z][k][n] + A[z][k][:] . B[z][:][n])
__global__ __launch_bounds__(256) void merge_T(
    const float* __restrict__ W, const float* __restrict__ A,
    const float* __restrict__ Bm, unsigned short* __restrict__ WT, int N) {
    __shared__ float t[32][132];
    const int z = blockIdx.z;
    W  += (size_t)z * 1024 * N;
    A  += (size_t)z * 1024 * 16;
    Bm += (size_t)z * 16 * N;
    WT += (size_t)z * N * 1024;
    int j0 = blockIdx.x * 128, i0 = blockIdx.y * 32;
    int tx = threadIdx.x & 31, ty = threadIdx.x >> 5;  // 32 x 8
    for (int ii = ty; ii < 32; ii += 8) {
        int i = i0 + ii;
        float4 acc = *(const float4*)&W[(size_t)i * N + j0 + tx * 4];
        #pragma unroll
        for (int r = 0; r < 16; r++) {
            float a = A[i * 16 + r];
            float4 bv = *(const float4*)&Bm[(size_t)r * N + j0 + tx * 4];
            acc.x += a * bv.x; acc.y += a * bv.y;
            acc.z += a * bv.z; acc.w += a * bv.w;
        }
        *(float4*)&t[ii][tx * 4] = acc;
    }
    __syncthreads();
    int jj = threadIdx.x >> 1, half = threadIdx.x & 1;
    bf16x8 o0, o1;
    #pragma unroll
    for (int c = 0; c < 8; c++) o0[c] = (short)f2bf(t[half * 16 + c][jj]);
    #pragma unroll
    for (int c = 0; c < 8; c++) o1[c] = (short)f2bf(t[half * 16 + 8 + c][jj]);
    unsigned short* dst = &WT[(size_t)(j0 + jj) * 1024 + i0 + half * 16];
    *(bf16x8*)dst = o0;
    *(bf16x8*)(dst + 8) = o1;
}

// ------------- GEMM 128x128, BK=64 (two m97-shape sub-buffers/barrier) -------------
__global__ __launch_bounds__(256) void gemm_bf16_128(
    const unsigned short* __restrict__ A,   // [M][K]
    const unsigned short* __restrict__ BT,  // [N][K]
    unsigned short* __restrict__ outB,      // bf16 out
    int M, int N, int K, int scaleq) {
    __shared__ __align__(16) unsigned short As[2][128 * 32];
    __shared__ __align__(16) unsigned short Bs[2][128 * 32];
    const int tid = threadIdx.x;
    const int m0 = blockIdx.y * 128, n0 = blockIdx.x * 128;
    const int w = tid >> 6, lane = tid & 63;
    const int wm = (w >> 1) * 64, wn = (w & 1) * 64;
    const int lr = lane & 15, quad = lane >> 4;
    const int srow = w * 16 + (lane >> 2);
    const int skof = (lane & 3) * 8;

    f32x4 acc[4][4] = {};

    for (int k0 = 0; k0 < K; k0 += 64) {
        __syncthreads();
        #pragma unroll
        for (int h = 0; h < 2; h++) {
            lds_stage16(A  + (size_t)(m0 + srow)      * K + k0 + h * 32 + skof,
                        (char*)As[h] + w * 1024);
            lds_stage16(A  + (size_t)(m0 + 64 + srow) * K + k0 + h * 32 + skof,
                        (char*)As[h] + 4096 + w * 1024);
            lds_stage16(BT + (size_t)(n0 + srow)      * K + k0 + h * 32 + skof,
                        (char*)Bs[h] + w * 1024);
            lds_stage16(BT + (size_t)(n0 + 64 + srow) * K + k0 + h * 32 + skof,
                        (char*)Bs[h] + 4096 + w * 1024);
        }
        __syncthreads();

        #pragma unroll
        for (int h = 0; h < 2; h++) {
            bf16x8 af[4], bfr[4];
            #pragma unroll
            for (int i = 0; i < 4; i++) {
                af[i]  = *(const bf16x8*)&As[h][(wm + i * 16 + lr) * 32 + quad * 8];
                bfr[i] = *(const bf16x8*)&Bs[h][(wn + i * 16 + lr) * 32 + quad * 8];
            }
            #pragma unroll
            for (int i = 0; i < 4; i++)
                #pragma unroll
                for (int j = 0; j < 4; j++)
                    acc[i][j] = mfma16(af[i], bfr[j], acc[i][j]);
        }
    }
    #pragma unroll
    for (int i = 0; i < 4; i++)
        #pragma unroll
        for (int j = 0; j < 4; j++)
            #pragma unroll
            for (int r = 0; r < 4; r++) {
                int row = m0 + wm + i * 16 + quad * 4 + r;
                int col = n0 + wn + j * 16 + lr;
                float v = acc[i][j][r];
                if (scaleq && col < 1024) v *= 0.125f;
                outB[(size_t)row * N + col] = f2bf(v);
            }
}

// ------------- GEMM 64x64, BK=64 (proj: 512 blocks, 2/CU) + residual -------------
__global__ __launch_bounds__(256) void gemm_bf16_64(
    const unsigned short* __restrict__ A,   // [M][K]
    const unsigned short* __restrict__ BT,  // [N][K]
    const float* __restrict__ res,          // [M][N] residual
    float* __restrict__ outF,               // fp32 out
    unsigned short* __restrict__ outB,      // bf16 out
    int M, int N, int K) {
    __shared__ __align__(16) unsigned short As[2][64 * 32];
    __shared__ __align__(16) unsigned short Bs[2][64 * 32];
    const int tid = threadIdx.x;
    const int m0 = blockIdx.y * 64, n0 = blockIdx.x * 64;
    const int w = tid >> 6, lane = tid & 63;
    const int wm = (w >> 1) * 32, wn = (w & 1) * 32;
    const int lr = lane & 15, quad = lane >> 4;
    const int srow = w * 16 + (lane >> 2);
    const int skof = (lane & 3) * 8;

    f32x4 acc[2][2] = {};

    for (int k0 = 0; k0 < K; k0 += 64) {
        __syncthreads();
        #pragma unroll
        for (int h = 0; h < 2; h++) {
            lds_stage16(A  + (size_t)(m0 + srow) * K + k0 + h * 32 + skof,
                        (char*)As[h] + w * 1024);
            lds_stage16(BT + (size_t)(n0 + srow) * K + k0 + h * 32 + skof,
                        (char*)Bs[h] + w * 1024);
        }
        __syncthreads();

        #pragma unroll
        for (int h = 0; h < 2; h++) {
            bf16x8 af[2], bfr[2];
            #pragma unroll
            for (int i = 0; i < 2; i++) {
                af[i]  = *(const bf16x8*)&As[h][(wm + i * 16 + lr) * 32 + quad * 8];
                bfr[i] = *(const bf16x8*)&Bs[h][(wn + i * 16 + lr) * 32 + quad * 8];
            }
            #pragma unroll
            for (int i = 0; i < 2; i++)
                #pragma unroll
                for (int j = 0; j < 2; j++)
                    acc[i][j] = mfma16(af[i], bfr[j], acc[i][j]);
        }
    }
    #pragma unroll
    for (int i = 0; i < 2; i++)
        #pragma unroll
        for (int j = 0; j < 2; j++)
            #pragma unroll
            for (int r = 0; r < 4; r++) {
                int row = m0 + wm + i * 16 + quad * 4 + r;
                int col = n0 + wn + j * 16 + lr;
                float v = acc[i][j][r] + res[(size_t)row * N + col];
                if (outF) outF[(size_t)row * N + col] = v;
                if (outB) outB[(size_t)row * N + col] = f2bf(v);
            }
}

// ------------- V transpose: VT[bh][d][s] -------------
__global__ __launch_bounds__(256) void vtrans(
    const unsigned short* __restrict__ qkv, unsigned short* __restrict__ VT) {
    __shared__ unsigned short t[32][33];
    int bh = blockIdx.z, b = bh >> 4, h = bh & 15;
    int s0 = blockIdx.x * 32, d0 = blockIdx.y * 32;
    int tx = threadIdx.x & 31, ty = threadIdx.x >> 5;
    for (int i = ty; i < 32; i += 8)
        t[i][tx] = qkv[(size_t)(b * 1024 + s0 + i) * 3072 + 2048 + h * 64 + d0 + tx];
    __syncthreads();
    for (int i = ty; i < 32; i += 8)
        VT[((size_t)bh * 64 + d0 + i) * 1024 + s0 + tx] = t[tx][i];
}

// ------------- Flash attention: 512 blocks, one 64-row q-block each -------------
// qblk = bh<16 ? x : 15-x  -> loads 1..16 mixed through dispatch order; greedy
// block scheduler + 2 blocks/CU (2 waves/SIMD) overlap the staging drains.
__global__ __launch_bounds__(256) void attn_kernel(
    const unsigned short* __restrict__ qkv,  // [2048][3072]
    const unsigned short* __restrict__ VT,   // [32][64][1024]
    unsigned short* __restrict__ O) {        // [2048][1024]
    __shared__ __align__(16) unsigned short Ks[2][64 * 32];  // [dhalf][s][d32]
    __shared__ __align__(16) unsigned short Vs[2][64 * 32];  // [shalf][d][s32]
    __shared__ __align__(16) unsigned short pl[4][16 * 72];
    const int tid = threadIdx.x;
    const int w = tid >> 6, lane = tid & 63;
    const int lr = lane & 15, quad = lane >> 4;
    const int bh = blockIdx.y, b = bh >> 4, h = bh & 15;
    const int qblk = (bh < 16) ? blockIdx.x : (15 - blockIdx.x);
    const int qb = qblk * 64 + w * 16;
    const int srow = w * 16 + (lane >> 2);
    const int skof = (lane & 3) * 8;
    const float LOG2E = 1.44269504f;

    const size_t rowQ = (size_t)(b * 1024 + qb + lr) * 3072 + h * 64;
    bf16x8 aq0 = *(const bf16x8*)&qkv[rowQ + quad * 8];
    bf16x8 aq1 = *(const bf16x8*)&qkv[rowQ + 32 + quad * 8];

    float m_i[4], l_i[4];
    f32x4 oacc[4] = {};
    #pragma unroll
    for (int r = 0; r < 4; r++) { m_i[r] = -1e30f; l_i[r] = 0.f; }

    const int nkt = qblk + 1;  // k-tiles of 64
    for (int kt64 = 0; kt64 < nkt; kt64++) {
        const int kt = kt64 << 6;
        __syncthreads();  // prev step's frag reads done
        const size_t gK = (size_t)(b * 1024 + kt + srow) * 3072 + 1024 + h * 64;
        lds_stage16(qkv + gK + skof,      (char*)Ks[0] + w * 1024);
        lds_stage16(qkv + gK + 32 + skof, (char*)Ks[1] + w * 1024);
        const size_t gV = ((size_t)bh * 64 + srow) * 1024 + kt;
        lds_stage16(VT + gV + skof,       (char*)Vs[0] + w * 1024);
        lds_stage16(VT + gV + 32 + skof,  (char*)Vs[1] + w * 1024);
        __syncthreads();  // drains vmcnt(0)

        // QK^T: 16 q-rows x 64 k-cols
        f32x4 s[4] = {};
        #pragma unroll
        for (int nh = 0; nh < 4; nh++) {
            bf16x8 kb0 = *(const bf16x8*)&Ks[0][(nh * 16 + lr) * 32 + quad * 8];
            bf16x8 kb1 = *(const bf16x8*)&Ks[1][(nh * 16 + lr) * 32 + quad * 8];
            s[nh] = mfma16(aq0, kb0, s[nh]);
            s[nh] = mfma16(aq1, kb1, s[nh]);
        }
        float mx[4];
        if (kt + 64 > qb) {  // diagonal tile: causal mask
            #pragma unroll
            for (int r = 0; r < 4; r++) {
                int qrow = qb + quad * 4 + r;
                #pragma unroll
                for (int nh = 0; nh < 4; nh++) {
                    int kcol = kt + nh * 16 + lr;
                    s[nh][r] = (kcol <= qrow) ? s[nh][r] : -1e30f;
                }
            }
        }
        #pragma unroll
        for (int r = 0; r < 4; r++) {
            mx[r] = fmaxf(fmaxf(s[0][r], s[1][r]), fmaxf(s[2][r], s[3][r]));
            RORMAX(mx[r], 0x121) RORMAX(mx[r], 0x122)
            RORMAX(mx[r], 0x124) RORMAX(mx[r], 0x128)
        }
        float al[4];
        #pragma unroll
        for (int r = 0; r < 4; r++) {
            float mnew = fmaxf(m_i[r], mx[r]);
            al[r] = exp2f((m_i[r] - mnew) * LOG2E);
            m_i[r] = mnew;
            float lsum = 0.f;
            #pragma unroll
            for (int nh = 0; nh < 4; nh++) {
                float p = exp2f((s[nh][r] - mnew) * LOG2E);
                s[nh][r] = p;
                lsum += p;
            }
            l_i[r] = l_i[r] * al[r] + lsum;  // lane-local partial
        }
        #pragma unroll
        for (int dt = 0; dt < 4; dt++)
            #pragma unroll
            for (int r = 0; r < 4; r++) oacc[dt][r] *= al[r];
        // P: C-layout -> LDS -> A-layout (wave-internal)
        #pragma unroll
        for (int nh = 0; nh < 4; nh++)
            #pragma unroll
            for (int r = 0; r < 4; r++)
                pl[w][(quad * 4 + r) * 72 + nh * 16 + lr] = f2bf(s[nh][r]);
        bf16x8 ap0 = *(const bf16x8*)&pl[w][lr * 72 + quad * 8];
        bf16x8 ap1 = *(const bf16x8*)&pl[w][lr * 72 + 32 + quad * 8];
        #pragma unroll
        for (int dt = 0; dt < 4; dt++) {
            bf16x8 vb0 = *(const bf16x8*)&Vs[0][(dt * 16 + lr) * 32 + quad * 8];
            bf16x8 vb1 = *(const bf16x8*)&Vs[1][(dt * 16 + lr) * 32 + quad * 8];
            oacc[dt] = mfma16(ap0, vb0, oacc[dt]);
            oacc[dt] = mfma16(ap1, vb1, oacc[dt]);
        }
    }
    // cross-lane finish of l (16 col-lanes per row group)
    #pragma unroll
    for (int r = 0; r < 4; r++) {
        RORADD(l_i[r], 0x121) RORADD(l_i[r], 0x122)
        RORADD(l_i[r], 0x124) RORADD(l_i[r], 0x128)
    }
    #pragma unroll
    for (int dt = 0; dt < 4; dt++)
        #pragma unroll
        for (int r = 0; r < 4; r++) {
            int row = b * 1024 + qb + quad * 4 + r;
            int col = h * 64 + dt * 16 + lr;
            O[(size_t)row * 1024 + col] = f2bf(oacc[dt][r] / l_i[r]);
        }
}

extern "C" void kernel_launch(void* const* d_in, const int* in_sizes, int n_in,
                              void* d_out, int out_size, void* d_ws, size_t ws_size,
                              hipStream_t stream) {
    const float* x     = (const float*)d_in[0];
    const float* Wqkv  = (const float*)d_in[1];
    const float* Aqkv  = (const float*)d_in[2];
    const float* Bqkv  = (const float*)d_in[3];
    const float* Wproj = (const float*)d_in[4];
    const float* Aproj = (const float*)d_in[5];
    const float* Bproj = (const float*)d_in[6];
    float* out = (float*)d_out;

    char* ws = (char*)d_ws;
    float* h_f32 = (float*)ws;                    ws += (size_t)2048 * 1024 * 4;
    unsigned short* h_bf   = (unsigned short*)ws; ws += (size_t)2048 * 1024 * 2;
    unsigned short* qkv_bf = (unsigned short*)ws; ws += (size_t)2048 * 3072 * 2;
    unsigned short* VT     = (unsigned short*)ws; ws += (size_t)32 * 64 * 1024 * 2;
    unsigned short* O_bf   = (unsigned short*)ws; ws += (size_t)2048 * 1024 * 2;
    unsigned short* WqT8   = (unsigned short*)ws; ws += (size_t)8 * 3072 * 1024 * 2;
    unsigned short* WpT8   = (unsigned short*)ws; ws += (size_t)8 * 1024 * 1024 * 2;

    convert_x<<<2048, 256, 0, stream>>>((const float4*)x, (float4*)h_f32,
                                        (ushort4*)h_bf, 2048 * 1024 / 4);
    // all layers' LoRA merges up front (independent of activations)
    merge_T<<<dim3(24, 32, 8), 256, 0, stream>>>(Wqkv, Aqkv, Bqkv, WqT8, 3072);
    merge_T<<<dim3(8, 32, 8), 256, 0, stream>>>(Wproj, Aproj, Bproj, WpT8, 1024);

    for (int l = 0; l < 8; l++) {
        const unsigned short* WqT = WqT8 + (size_t)l * 3072 * 1024;
        const unsigned short* WpT = WpT8 + (size_t)l * 1024 * 1024;
        // qkv GEMM: Q columns pre-scaled by 1/8
        gemm_bf16_128<<<dim3(24, 16), 256, 0, stream>>>(h_bf, WqT, qkv_bf,
                                                        2048, 3072, 1024, 1);
        vtrans<<<dim3(32, 2, 32), 256, 0, stream>>>(qkv_bf, VT);
        attn_kernel<<<dim3(16, 32), 256, 0, stream>>>(qkv_bf, VT, O_bf);
        float* outF = (l == 7) ? out : h_f32;
        gemm_bf16_64<<<dim3(16, 32), 256, 0, stream>>>(O_bf, WpT, h_f32, outF,
                                                       h_bf, 2048, 1024, 1024);
    }
}